// Round 6
// baseline (714.641 us; speedup 1.0000x reference)
//
#include <hip/hip_runtime.h>
#include <math.h>

typedef int i32x4 __attribute__((ext_vector_type(4)));
typedef unsigned long long u64;

constexpr int TT = 4;
constexpr int BB = 32;
constexpr int CC = 384;
constexpr int NN = 256;
constexpr int HEADS = 8;
constexpr int HD = 48;
constexpr int BCN = BB * CC * NN;
constexpr int TBCN = TT * BCN;          // 12,582,912
constexpr int CCC = CC * CC;            // 147,456
constexpr float MARGIN = 1e-3f;         // LIF decision margin that triggers np-exact recompute
constexpr unsigned FCAP = 262144;       // flag list capacity

// ---------------------------------------------------------------------------
// LDS overlay (tile: 64 o x 32 n x 4 t, 3 digit planes)
// ---------------------------------------------------------------------------
union LdsU {
    struct {
        unsigned char W8[3][64][40];   // weight digit planes [pl][o][k] (+8B pad)
        unsigned char S8[4][32][40];   // spikes [t][n][k] (+8B pad)
    } st;
    unsigned char R[4][32][64];        // spike repack [t][n][c]
};

// ---------------------------------------------------------------------------
// Kernel 0: quantize fp32 weights -> 3 signed-i8 digit planes of round(w*2^23)
// Also zeroes the flag counter.
// ---------------------------------------------------------------------------
__global__ __launch_bounds__(256) void k_wsplit(
    const float* __restrict__ qw, const float* __restrict__ kw,
    const float* __restrict__ vw, const float* __restrict__ pw,
    signed char* __restrict__ wq, unsigned* __restrict__ cnt) {
    if (blockIdx.x == 0 && threadIdx.x == 0) *cnt = 0u;
    int idx = blockIdx.x * 256 + threadIdx.x;     // 4*CCC total
    int mat = idx / CCC, r = idx % CCC;
    const float* src = (mat == 0) ? qw : (mat == 1) ? kw : (mat == 2) ? vw : pw;
    double w = (double)src[r];
    long long W = llround(w * 8388608.0);         // w * 2^23 (|w| < 0.99)
    signed char d0 = (signed char)(W & 0xff); W = (W - d0) >> 8;
    signed char d1 = (signed char)(W & 0xff); W = (W - d1) >> 8;
    signed char d2 = (signed char)W;              // |d2| <= 64 for |w|<1
    size_t base = (size_t)mat * 3 * CCC;
    wq[base + 0 * CCC + r] = d0;
    wq[base + 1 * CCC + r] = d1;
    wq[base + 2 * CCC + r] = d2;
}

// ---------------------------------------------------------------------------
// Kernel 1: shortcut LIF on x [t,b,c,n] -> u8 spikes xs in [t,b,n,c]
// fp32 ops in exact np order (products/halvings exact; adds round like np).
// ---------------------------------------------------------------------------
__global__ __launch_bounds__(256) void k_lif_x(const float* __restrict__ x,
                                               unsigned char* __restrict__ xs) {
    __shared__ unsigned char sL[4][64][64];
    const int b_ = blockIdx.x, c0 = blockIdx.y * 64, n0 = blockIdx.z * 64;
    const int tid = threadIdx.x;

    float vm[4][4];
#pragma unroll
    for (int a = 0; a < 4; ++a)
#pragma unroll
        for (int j = 0; j < 4; ++j) vm[a][j] = 0.f;

#pragma unroll
    for (int t = 0; t < TT; ++t) {
#pragma unroll
        for (int a = 0; a < 4; ++a) {
            int idx = tid + 256 * a;
            int ci = idx >> 4, nj4 = idx & 15;
            float4 xv = *(const float4*)&x[((size_t)((t * BB + b_) * CC) + c0 + ci) * NN + n0 + nj4 * 4];
            float xa[4] = {xv.x, xv.y, xv.z, xv.w};
#pragma unroll
            for (int j = 0; j < 4; ++j) {
                vm[a][j] = __fadd_rn(vm[a][j], __fmul_rn(__fsub_rn(xa[j], vm[a][j]), 0.5f));
                int s = (vm[a][j] >= 0.5f);
                sL[t][nj4 * 4 + j][ci] = (unsigned char)s;
                if (s) vm[a][j] = 0.f;
            }
        }
    }
    __syncthreads();
#pragma unroll
    for (int i = 0; i < 16; ++i) {
        int s = tid + 256 * i;
        int c4 = s & 15, n = (s >> 4) & 63, t = s >> 10;
        *(uchar4*)&xs[((size_t)((t * BB + b_) * NN) + n0 + n) * CC + c0 + c4 * 4] =
            *(const uchar4*)&sL[t][n][c4 * 4];
    }
}

// ---------------------------------------------------------------------------
// Kernel 2: branch GEMM, 3-plane i8 MFMA + fp32(np-order) BN+LIF -> u8 [t,b,n,c]
// Near-threshold trajectories get flagged for np-exact recompute.
// Block 256 = 4 waves; tile 64 o x 32 n x 4 t; grid (B, 6, 8).
// ---------------------------------------------------------------------------
__global__ __launch_bounds__(256, 2) void k_branch_i8(
    const unsigned char* __restrict__ xs, const signed char* __restrict__ wq,
    const float* __restrict__ gg, const float* __restrict__ bbp,
    const float* __restrict__ mmp, const float* __restrict__ vvp,
    unsigned char* __restrict__ spk, int mat,
    unsigned* __restrict__ cnt, unsigned* __restrict__ list) {
    __shared__ LdsU L;
    const int b_ = blockIdx.x, ob = blockIdx.y * 64, nb = blockIdx.z * 32;
    const int tid = threadIdx.x, lane = tid & 63, w = tid >> 6;
    const int lo16 = lane & 15, hi4 = lane >> 4;

    i32x4 acc[3][4][2];
#pragma unroll
    for (int p = 0; p < 3; ++p)
#pragma unroll
        for (int t = 0; t < 4; ++t)
#pragma unroll
            for (int nf = 0; nf < 2; ++nf) acc[p][t][nf] = (i32x4){0, 0, 0, 0};

    for (int k0 = 0; k0 < CC; k0 += 32) {
#pragma unroll
        for (int pl = 0; pl < 3; ++pl) {   // stage 3 weight digit planes [64][32]
            int o = tid >> 2, kg = tid & 3;
            u64 v = *(const u64*)&wq[(size_t)pl * CCC + (size_t)(ob + o) * CC + k0 + kg * 8];
            *(u64*)&L.st.W8[pl][o][kg * 8] = v;
        }
#pragma unroll
        for (int i = 0; i < 2; ++i) {      // stage spikes [4][32][32]
            int e = tid + 256 * i;
            int t = e >> 7, rem = e & 127, n = rem >> 2, kg = rem & 3;
            u64 v = *(const u64*)&xs[((size_t)((t * BB + b_) * NN) + nb + n) * CC + k0 + kg * 8];
            *(u64*)&L.st.S8[t][n][kg * 8] = v;
        }
        __syncthreads();
        u64 af0 = *(const u64*)&L.st.W8[0][w * 16 + lo16][hi4 * 8];
        u64 af1 = *(const u64*)&L.st.W8[1][w * 16 + lo16][hi4 * 8];
        u64 af2 = *(const u64*)&L.st.W8[2][w * 16 + lo16][hi4 * 8];
#pragma unroll
        for (int t = 0; t < 4; ++t)
#pragma unroll
            for (int nf = 0; nf < 2; ++nf) {
                u64 bfr = *(const u64*)&L.st.S8[t][nf * 16 + lo16][hi4 * 8];
                acc[0][t][nf] = __builtin_amdgcn_mfma_i32_16x16x32_i8((long)af0, (long)bfr, acc[0][t][nf], 0, 0, 0);
                acc[1][t][nf] = __builtin_amdgcn_mfma_i32_16x16x32_i8((long)af1, (long)bfr, acc[1][t][nf], 0, 0, 0);
                acc[2][t][nf] = __builtin_amdgcn_mfma_i32_16x16x32_i8((long)af2, (long)bfr, acc[2][t][nf], 0, 0, 0);
            }
        __syncthreads();
    }

    // epilogue: fp32 np-order BN + LIF, margin flagging, spikes into LDS repack
#pragma unroll
    for (int r = 0; r < 4; ++r) {
        const int o = ob + w * 16 + hi4 * 4 + r;
        const float inv = __fdiv_rn(gg[o], __fsqrt_rn(__fadd_rn(vvp[o], 1e-5f)));
        const float mu = mmp[o], be = bbp[o];
#pragma unroll
        for (int nf = 0; nf < 2; ++nf) {
            float vmem = 0.f, mg = 1e9f;
#pragma unroll
            for (int t = 0; t < 4; ++t) {
                long long N = (long long)acc[0][t][nf][r] + 256LL * acc[1][t][nf][r]
                            + 65536LL * acc[2][t][nf][r];
                float dotf = (float)((double)N * 0x1p-23);
                float y = __fadd_rn(__fmul_rn(__fsub_rn(dotf, mu), inv), be);
                vmem = __fadd_rn(vmem, __fmul_rn(__fsub_rn(y, vmem), 0.5f));
                mg = fminf(mg, fabsf(__fsub_rn(vmem, 0.5f)));
                int s = (vmem >= 0.5f);
                L.R[t][nf * 16 + lo16][w * 16 + hi4 * 4 + r] = (unsigned char)s;
                if (s) vmem = 0.f;
            }
            if (mg < MARGIN) {
                unsigned idx = atomicAdd(cnt, 1u);
                int n = nb + nf * 16 + lo16;
                if (idx < FCAP) list[idx] = ((unsigned)mat << 22) | ((unsigned)b_ << 17) |
                                            ((unsigned)o << 8) | (unsigned)n;
            }
        }
    }
    __syncthreads();
#pragma unroll
    for (int i = 0; i < 8; ++i) {
        int e = tid + 256 * i;
        int c4 = e & 15, n = (e >> 4) & 31, t = e >> 9;
        *(uchar4*)&spk[((size_t)((t * BB + b_) * NN) + nb + n) * CC + ob + c4 * 4] =
            *(const uchar4*)&L.R[t][n][c4 * 4];
    }
}

// ---------------------------------------------------------------------------
// Kernel 2b: np-exact fixup of flagged trajectories (sequential-c fp32 dot)
// ---------------------------------------------------------------------------
__global__ __launch_bounds__(256) void k_fixup(
    const unsigned char* __restrict__ xs,
    const float* __restrict__ qw, const float* __restrict__ kw, const float* __restrict__ vw,
    const float* __restrict__ qg, const float* __restrict__ qb,
    const float* __restrict__ qm, const float* __restrict__ qv,
    const float* __restrict__ kg_, const float* __restrict__ kb_,
    const float* __restrict__ km_, const float* __restrict__ kv_,
    const float* __restrict__ vg, const float* __restrict__ vb,
    const float* __restrict__ vm_, const float* __restrict__ vv_,
    unsigned char* __restrict__ qs, unsigned char* __restrict__ ks,
    unsigned char* __restrict__ vs,
    const unsigned* __restrict__ cnt, const unsigned* __restrict__ list) {
    unsigned nfl = *cnt;
    if (nfl > FCAP) nfl = FCAP;
    for (unsigned i = blockIdx.x * 256 + threadIdx.x; i < nfl; i += gridDim.x * 256) {
        unsigned e = list[i];
        int mat = e >> 22, b_ = (e >> 17) & 31, o = (e >> 8) & 511, n = e & 255;
        const float* wbase = (mat == 0) ? qw : (mat == 1) ? kw : vw;
        const float* G = (mat == 0) ? qg : (mat == 1) ? kg_ : vg;
        const float* Bb = (mat == 0) ? qb : (mat == 1) ? kb_ : vb;
        const float* M = (mat == 0) ? qm : (mat == 1) ? km_ : vm_;
        const float* V = (mat == 0) ? qv : (mat == 1) ? kv_ : vv_;
        unsigned char* S = (mat == 0) ? qs : (mat == 1) ? ks : vs;
        const float inv = __fdiv_rn(G[o], __fsqrt_rn(__fadd_rn(V[o], 1e-5f)));
        const float mu = M[o], be = Bb[o];
        const float* wrow = wbase + (size_t)o * CC;
        float vmem = 0.f;
        for (int t = 0; t < TT; ++t) {
            const unsigned char* xr = xs + ((size_t)((t * BB + b_) * NN) + n) * CC;
            float acc = 0.f;
            for (int c = 0; c < CC; ++c)
                if (xr[c]) acc = __fadd_rn(acc, wrow[c]);
            float y = __fadd_rn(__fmul_rn(__fsub_rn(acc, mu), inv), be);
            vmem = __fadd_rn(vmem, __fmul_rn(__fsub_rn(y, vmem), 0.5f));
            int s = (vmem >= 0.5f);
            S[((size_t)((t * BB + b_) * NN) + n) * CC + o] = (unsigned char)s;
            if (s) vmem = 0.f;
        }
    }
}

// ---------------------------------------------------------------------------
// Kernel 3: v spikes [t,b,n,c] u8 -> f32 out [t,b,h,n,d]
// ---------------------------------------------------------------------------
__global__ __launch_bounds__(256) void k_vout(const unsigned char* __restrict__ vs,
                                              float* __restrict__ vout) {
    int e = blockIdx.x * 256 + threadIdx.x;
    int d4 = e % 12;
    int r = e / 12;
    int n = r & 255;
    r >>= 8;
    int h = r & 7;
    int tb = r >> 3;
    uchar4 u = *(const uchar4*)&vs[((size_t)tb * NN + n) * CC + h * HD + d4 * 4];
    float4 o = {(float)u.x, (float)u.y, (float)u.z, (float)u.w};
    *(float4*)&vout[(((size_t)tb * HEADS + h) * NN + n) * HD + d4 * 4] = o;
}

// ---------------------------------------------------------------------------
// Kernel 4: kvsum[t,b,c] = sum_n k*v  (exact integer)
// ---------------------------------------------------------------------------
__global__ __launch_bounds__(256) void k_kvsum(const unsigned char* __restrict__ ks,
                                               const unsigned char* __restrict__ vs,
                                               int* __restrict__ kvsum) {
    __shared__ int P[5][CC];
    const int tb = blockIdx.x, tid = threadIdx.x;
    if (tid < 240) {
        int c8 = tid % 48, sl = tid / 48;
        int a[8] = {0, 0, 0, 0, 0, 0, 0, 0};
        for (int n = sl; n < NN; n += 5) {
            u64 kk = *(const u64*)&ks[((size_t)tb * NN + n) * CC + c8 * 8];
            u64 vvv = *(const u64*)&vs[((size_t)tb * NN + n) * CC + c8 * 8];
            u64 u = kk & vvv;
#pragma unroll
            for (int j = 0; j < 8; ++j) a[j] += (int)((u >> (8 * j)) & 1);
        }
#pragma unroll
        for (int j = 0; j < 8; ++j) P[sl][c8 * 8 + j] = a[j];
    }
    __syncthreads();
    for (int c = tid; c < CC; c += 256) {
        kvsum[(size_t)tb * CC + c] = P[0][c] + P[1][c] + P[2][c] + P[3][c] + P[4][c];
    }
}

// ---------------------------------------------------------------------------
// Kernel 5: talking heads + LIF, fp32 np-order (sequential h, rounded products)
// ---------------------------------------------------------------------------
__global__ __launch_bounds__(384) void k_thlif(const int* __restrict__ kvsum,
                                               const float* __restrict__ th,
                                               unsigned char* __restrict__ kvm) {
    __shared__ int kv0[TT][CC];
    const int b_ = blockIdx.x, c = threadIdx.x;
#pragma unroll
    for (int t = 0; t < TT; ++t) kv0[t][c] = kvsum[(size_t)(t * BB + b_) * CC + c];
    __syncthreads();
    const int ho = c / HD, d = c % HD;
    float vmem = 0.f;
#pragma unroll
    for (int t = 0; t < TT; ++t) {
        float s = 0.f;
#pragma unroll
        for (int h = 0; h < HEADS; ++h)
            s = __fadd_rn(s, __fmul_rn(th[ho * HEADS + h], (float)kv0[t][h * HD + d]));
        vmem = __fadd_rn(vmem, __fmul_rn(__fsub_rn(s, vmem), 0.5f));
        int sp = (vmem >= 0.5f);
        kvm[(size_t)(t * BB + b_) * CC + c] = (unsigned char)sp;
        if (sp) vmem = 0.f;
    }
}

// ---------------------------------------------------------------------------
// Kernel 6: proj GEMM (3-plane i8 on q & kvmask); fp64 epilogue:
// +bias, BN, +identity -> f32 out [t,b,c,n]  (real-valued; no decisions)
// ---------------------------------------------------------------------------
__global__ __launch_bounds__(256, 2) void k_proj_i8(
    const unsigned char* __restrict__ qs, const unsigned char* __restrict__ kvm,
    const signed char* __restrict__ wq, const float* __restrict__ pbias,
    const float* __restrict__ gg, const float* __restrict__ bbp,
    const float* __restrict__ mmp, const float* __restrict__ vvp,
    const float* __restrict__ xin, float* __restrict__ out) {
    __shared__ LdsU L;
    const int b_ = blockIdx.x, ob = blockIdx.y * 64, nb = blockIdx.z * 32;
    const int tid = threadIdx.x, lane = tid & 63, w = tid >> 6;
    const int lo16 = lane & 15, hi4 = lane >> 4;

    i32x4 acc[3][4][2];
#pragma unroll
    for (int p = 0; p < 3; ++p)
#pragma unroll
        for (int t = 0; t < 4; ++t)
#pragma unroll
            for (int nf = 0; nf < 2; ++nf) acc[p][t][nf] = (i32x4){0, 0, 0, 0};

    for (int k0 = 0; k0 < CC; k0 += 32) {
#pragma unroll
        for (int pl = 0; pl < 3; ++pl) {
            int o = tid >> 2, kg = tid & 3;
            u64 v = *(const u64*)&wq[(size_t)pl * CCC + (size_t)(ob + o) * CC + k0 + kg * 8];
            *(u64*)&L.st.W8[pl][o][kg * 8] = v;
        }
#pragma unroll
        for (int i = 0; i < 2; ++i) {
            int e = tid + 256 * i;
            int t = e >> 7, rem = e & 127, n = rem >> 2, kg = rem & 3;
            u64 uq = *(const u64*)&qs[((size_t)((t * BB + b_) * NN) + nb + n) * CC + k0 + kg * 8];
            u64 um = *(const u64*)&kvm[(size_t)(t * BB + b_) * CC + k0 + kg * 8];
            *(u64*)&L.st.S8[t][n][kg * 8] = uq & um;
        }
        __syncthreads();
        u64 af0 = *(const u64*)&L.st.W8[0][w * 16 + lo16][hi4 * 8];
        u64 af1 = *(const u64*)&L.st.W8[1][w * 16 + lo16][hi4 * 8];
        u64 af2 = *(const u64*)&L.st.W8[2][w * 16 + lo16][hi4 * 8];
#pragma unroll
        for (int t = 0; t < 4; ++t)
#pragma unroll
            for (int nf = 0; nf < 2; ++nf) {
                u64 bfr = *(const u64*)&L.st.S8[t][nf * 16 + lo16][hi4 * 8];
                acc[0][t][nf] = __builtin_amdgcn_mfma_i32_16x16x32_i8((long)af0, (long)bfr, acc[0][t][nf], 0, 0, 0);
                acc[1][t][nf] = __builtin_amdgcn_mfma_i32_16x16x32_i8((long)af1, (long)bfr, acc[1][t][nf], 0, 0, 0);
                acc[2][t][nf] = __builtin_amdgcn_mfma_i32_16x16x32_i8((long)af2, (long)bfr, acc[2][t][nf], 0, 0, 0);
            }
        __syncthreads();
    }

#pragma unroll
    for (int r = 0; r < 4; ++r) {
        const int o = ob + w * 16 + hi4 * 4 + r;
        const double inv = (double)gg[o] / sqrt((double)vvp[o] + 1e-5);
        const double mu = (double)mmp[o], be = (double)bbp[o], pb = (double)pbias[o];
#pragma unroll
        for (int nf = 0; nf < 2; ++nf) {
#pragma unroll
            for (int t = 0; t < 4; ++t) {
                long long N = (long long)acc[0][t][nf][r] + 256LL * acc[1][t][nf][r]
                            + 65536LL * acc[2][t][nf][r];
                double tot = (double)N * 0x1p-23;
                size_t idx = ((size_t)((t * BB + b_) * CC) + o) * NN + nb + nf * 16 + lo16;
                double y = (tot + pb - mu) * inv + be;
                out[idx] = (float)(y + (double)xin[idx]);
            }
        }
    }
}

// ---------------------------------------------------------------------------
extern "C" void kernel_launch(void* const* d_in, const int* in_sizes, int n_in,
                              void* d_out, int out_size, void* d_ws, size_t ws_size,
                              hipStream_t stream) {
    const float* x    = (const float*)d_in[0];
    const float* q_w  = (const float*)d_in[1];
    const float* k_w  = (const float*)d_in[2];
    const float* v_w  = (const float*)d_in[3];
    const float* q_g  = (const float*)d_in[4];
    const float* q_b  = (const float*)d_in[5];
    const float* q_m  = (const float*)d_in[6];
    const float* q_v  = (const float*)d_in[7];
    const float* k_g  = (const float*)d_in[8];
    const float* k_b  = (const float*)d_in[9];
    const float* k_m  = (const float*)d_in[10];
    const float* k_v  = (const float*)d_in[11];
    const float* v_g  = (const float*)d_in[12];
    const float* v_b  = (const float*)d_in[13];
    const float* v_m  = (const float*)d_in[14];
    const float* v_v  = (const float*)d_in[15];
    const float* p_g  = (const float*)d_in[16];
    const float* p_b  = (const float*)d_in[17];
    const float* p_m  = (const float*)d_in[18];
    const float* p_v  = (const float*)d_in[19];
    const float* th_w = (const float*)d_in[20];
    const float* pr_w = (const float*)d_in[21];
    const float* pr_b = (const float*)d_in[22];

    float* out  = (float*)d_out;
    float* vout = out + (size_t)TBCN;

    unsigned char* ws  = (unsigned char*)d_ws;
    unsigned char* xs  = ws;
    unsigned char* qs  = ws + (size_t)TBCN;
    unsigned char* ks2 = ws + (size_t)2 * TBCN;
    unsigned char* vs2 = ws + (size_t)3 * TBCN;
    signed char* wq    = (signed char*)(ws + (size_t)4 * TBCN);          // 4 mats * 3*CCC
    int* kvsum         = (int*)(ws + (size_t)4 * TBCN + 12ull * CCC);
    unsigned char* kvm = (unsigned char*)(kvsum + TT * BB * CC);
    unsigned* fcnt     = (unsigned*)(kvm + (size_t)TT * BB * CC + 64);
    unsigned* flist    = fcnt + 16;

    k_wsplit<<<(4 * CCC) / 256, 256, 0, stream>>>(q_w, k_w, v_w, pr_w, wq, fcnt);
    k_lif_x<<<dim3(BB, CC / 64, NN / 64), 256, 0, stream>>>(x, xs);

    dim3 gg(BB, CC / 64, NN / 32);
    k_branch_i8<<<gg, 256, 0, stream>>>(xs, wq + 0ull * 3 * CCC, q_g, q_b, q_m, q_v, qs, 0, fcnt, flist);
    k_branch_i8<<<gg, 256, 0, stream>>>(xs, wq + 1ull * 3 * CCC, k_g, k_b, k_m, k_v, ks2, 1, fcnt, flist);
    k_branch_i8<<<gg, 256, 0, stream>>>(xs, wq + 2ull * 3 * CCC, v_g, v_b, v_m, v_v, vs2, 2, fcnt, flist);

    k_fixup<<<64, 256, 0, stream>>>(xs, q_w, k_w, v_w,
                                    q_g, q_b, q_m, q_v,
                                    k_g, k_b, k_m, k_v,
                                    v_g, v_b, v_m, v_v,
                                    qs, ks2, vs2, fcnt, flist);

    k_vout<<<(TBCN / 4) / 256, 256, 0, stream>>>(vs2, vout);
    k_kvsum<<<TT * BB, 256, 0, stream>>>(ks2, vs2, kvsum);
    k_thlif<<<BB, CC, 0, stream>>>(kvsum, th_w, kvm);

    k_proj_i8<<<gg, 256, 0, stream>>>(qs, kvm, wq + 3ull * 3 * CCC, pr_b,
                                      p_g, p_b, p_m, p_v, x, out);
}

// Round 7
// 337.943 us; speedup vs baseline: 2.1147x; 2.1147x over previous
//
#include <hip/hip_runtime.h>
#include <math.h>

typedef int i32x4 __attribute__((ext_vector_type(4)));
typedef unsigned long long u64;

constexpr int TT = 4;
constexpr int BB = 32;
constexpr int CC = 384;
constexpr int NN = 256;
constexpr int HEADS = 8;
constexpr int HD = 48;
constexpr int BCN = BB * CC * NN;
constexpr int TBCN = TT * BCN;          // 12,582,912
constexpr int CCC = CC * CC;            // 147,456
constexpr float MARGIN = 3e-4f;         // LIF margin triggering np-exact recompute
                                        // (i8-path vs seq-c fp32 deviation <= ~6e-5)
constexpr unsigned FCAP = 262144;       // flag list capacity

// ---------------------------------------------------------------------------
// LDS overlay (tile: 64 o x 32 n x 4 t, 3 digit planes)
// ---------------------------------------------------------------------------
union LdsU {
    struct {
        unsigned char W8[3][64][40];   // weight digit planes [pl][o][k] (+8B pad)
        unsigned char S8[4][32][40];   // spikes [t][n][k] (+8B pad)
    } st;
    unsigned char R[4][32][64];        // spike repack [t][n][c]
};

// ---------------------------------------------------------------------------
// Kernel 0: quantize fp32 weights -> 3 signed-i8 digit planes of round(w*2^23)
// Also zeroes the flag counter.
// ---------------------------------------------------------------------------
__global__ __launch_bounds__(256) void k_wsplit(
    const float* __restrict__ qw, const float* __restrict__ kw,
    const float* __restrict__ vw, const float* __restrict__ pw,
    signed char* __restrict__ wq, unsigned* __restrict__ cnt) {
    if (blockIdx.x == 0 && threadIdx.x == 0) *cnt = 0u;
    int idx = blockIdx.x * 256 + threadIdx.x;     // 4*CCC total
    int mat = idx / CCC, r = idx % CCC;
    const float* src = (mat == 0) ? qw : (mat == 1) ? kw : (mat == 2) ? vw : pw;
    double w = (double)src[r];
    long long W = llround(w * 8388608.0);         // w * 2^23 (|w| < 0.99)
    signed char d0 = (signed char)(W & 0xff); W = (W - d0) >> 8;
    signed char d1 = (signed char)(W & 0xff); W = (W - d1) >> 8;
    signed char d2 = (signed char)W;              // |d2| <= 64 for |w|<1
    size_t base = (size_t)mat * 3 * CCC;
    wq[base + 0 * CCC + r] = d0;
    wq[base + 1 * CCC + r] = d1;
    wq[base + 2 * CCC + r] = d2;
}

// ---------------------------------------------------------------------------
// Kernel 1: shortcut LIF on x [t,b,c,n] -> u8 spikes xs in [t,b,n,c]
// fp32 ops in exact np order.
// ---------------------------------------------------------------------------
__global__ __launch_bounds__(256) void k_lif_x(const float* __restrict__ x,
                                               unsigned char* __restrict__ xs) {
    __shared__ unsigned char sL[4][64][64];
    const int b_ = blockIdx.x, c0 = blockIdx.y * 64, n0 = blockIdx.z * 64;
    const int tid = threadIdx.x;

    float vm[4][4];
#pragma unroll
    for (int a = 0; a < 4; ++a)
#pragma unroll
        for (int j = 0; j < 4; ++j) vm[a][j] = 0.f;

#pragma unroll
    for (int t = 0; t < TT; ++t) {
#pragma unroll
        for (int a = 0; a < 4; ++a) {
            int idx = tid + 256 * a;
            int ci = idx >> 4, nj4 = idx & 15;
            float4 xv = *(const float4*)&x[((size_t)((t * BB + b_) * CC) + c0 + ci) * NN + n0 + nj4 * 4];
            float xa[4] = {xv.x, xv.y, xv.z, xv.w};
#pragma unroll
            for (int j = 0; j < 4; ++j) {
                vm[a][j] = __fadd_rn(vm[a][j], __fmul_rn(__fsub_rn(xa[j], vm[a][j]), 0.5f));
                int s = (vm[a][j] >= 0.5f);
                sL[t][nj4 * 4 + j][ci] = (unsigned char)s;
                if (s) vm[a][j] = 0.f;
            }
        }
    }
    __syncthreads();
#pragma unroll
    for (int i = 0; i < 16; ++i) {
        int s = tid + 256 * i;
        int c4 = s & 15, n = (s >> 4) & 63, t = s >> 10;
        *(uchar4*)&xs[((size_t)((t * BB + b_) * NN) + n0 + n) * CC + c0 + c4 * 4] =
            *(const uchar4*)&sL[t][n][c4 * 4];
    }
}

// ---------------------------------------------------------------------------
// Kernel 2: branch GEMM, 3-plane i8 MFMA + fp32(np-order) BN+LIF -> u8 [t,b,n,c]
// Near-threshold trajectories flagged for np-exact recompute.
// ---------------------------------------------------------------------------
__global__ __launch_bounds__(256, 2) void k_branch_i8(
    const unsigned char* __restrict__ xs, const signed char* __restrict__ wq,
    const float* __restrict__ gg, const float* __restrict__ bbp,
    const float* __restrict__ mmp, const float* __restrict__ vvp,
    unsigned char* __restrict__ spk, int mat,
    unsigned* __restrict__ cnt, unsigned* __restrict__ list) {
    __shared__ LdsU L;
    const int b_ = blockIdx.x, ob = blockIdx.y * 64, nb = blockIdx.z * 32;
    const int tid = threadIdx.x, lane = tid & 63, w = tid >> 6;
    const int lo16 = lane & 15, hi4 = lane >> 4;

    i32x4 acc[3][4][2];
#pragma unroll
    for (int p = 0; p < 3; ++p)
#pragma unroll
        for (int t = 0; t < 4; ++t)
#pragma unroll
            for (int nf = 0; nf < 2; ++nf) acc[p][t][nf] = (i32x4){0, 0, 0, 0};

    for (int k0 = 0; k0 < CC; k0 += 32) {
#pragma unroll
        for (int pl = 0; pl < 3; ++pl) {   // stage 3 weight digit planes [64][32]
            int o = tid >> 2, kg = tid & 3;
            u64 v = *(const u64*)&wq[(size_t)pl * CCC + (size_t)(ob + o) * CC + k0 + kg * 8];
            *(u64*)&L.st.W8[pl][o][kg * 8] = v;
        }
#pragma unroll
        for (int i = 0; i < 2; ++i) {      // stage spikes [4][32][32]
            int e = tid + 256 * i;
            int t = e >> 7, rem = e & 127, n = rem >> 2, kg = rem & 3;
            u64 v = *(const u64*)&xs[((size_t)((t * BB + b_) * NN) + nb + n) * CC + k0 + kg * 8];
            *(u64*)&L.st.S8[t][n][kg * 8] = v;
        }
        __syncthreads();
        u64 af0 = *(const u64*)&L.st.W8[0][w * 16 + lo16][hi4 * 8];
        u64 af1 = *(const u64*)&L.st.W8[1][w * 16 + lo16][hi4 * 8];
        u64 af2 = *(const u64*)&L.st.W8[2][w * 16 + lo16][hi4 * 8];
#pragma unroll
        for (int t = 0; t < 4; ++t)
#pragma unroll
            for (int nf = 0; nf < 2; ++nf) {
                u64 bfr = *(const u64*)&L.st.S8[t][nf * 16 + lo16][hi4 * 8];
                acc[0][t][nf] = __builtin_amdgcn_mfma_i32_16x16x32_i8((long)af0, (long)bfr, acc[0][t][nf], 0, 0, 0);
                acc[1][t][nf] = __builtin_amdgcn_mfma_i32_16x16x32_i8((long)af1, (long)bfr, acc[1][t][nf], 0, 0, 0);
                acc[2][t][nf] = __builtin_amdgcn_mfma_i32_16x16x32_i8((long)af2, (long)bfr, acc[2][t][nf], 0, 0, 0);
            }
        __syncthreads();
    }

    // epilogue: fp32 np-order BN + LIF, margin flagging, spikes into LDS repack
#pragma unroll
    for (int r = 0; r < 4; ++r) {
        const int o = ob + w * 16 + hi4 * 4 + r;
        const float inv = __fdiv_rn(gg[o], __fsqrt_rn(__fadd_rn(vvp[o], 1e-5f)));
        const float mu = mmp[o], be = bbp[o];
#pragma unroll
        for (int nf = 0; nf < 2; ++nf) {
            float vmem = 0.f, mg = 1e9f;
#pragma unroll
            for (int t = 0; t < 4; ++t) {
                long long N = (long long)acc[0][t][nf][r] + 256LL * acc[1][t][nf][r]
                            + 65536LL * acc[2][t][nf][r];
                float dotf = (float)((double)N * 0x1p-23);
                float y = __fadd_rn(__fmul_rn(__fsub_rn(dotf, mu), inv), be);
                vmem = __fadd_rn(vmem, __fmul_rn(__fsub_rn(y, vmem), 0.5f));
                mg = fminf(mg, fabsf(__fsub_rn(vmem, 0.5f)));
                int s = (vmem >= 0.5f);
                L.R[t][nf * 16 + lo16][w * 16 + hi4 * 4 + r] = (unsigned char)s;
                if (s) vmem = 0.f;
            }
            if (mg < MARGIN) {
                unsigned idx = atomicAdd(cnt, 1u);
                int n = nb + nf * 16 + lo16;
                if (idx < FCAP) list[idx] = ((unsigned)mat << 22) | ((unsigned)b_ << 17) |
                                            ((unsigned)o << 8) | (unsigned)n;
            }
        }
    }
    __syncthreads();
#pragma unroll
    for (int i = 0; i < 8; ++i) {
        int e = tid + 256 * i;
        int c4 = e & 15, n = (e >> 4) & 31, t = e >> 9;
        *(uchar4*)&spk[((size_t)((t * BB + b_) * NN) + nb + n) * CC + ob + c4 * 4] =
            *(const uchar4*)&L.R[t][n][c4 * 4];
    }
}

// ---------------------------------------------------------------------------
// Kernel 2b: np-exact fixup of flagged trajectories.
// One BLOCK per item: 256 threads stage wrow + 4 xs rows into LDS, then
// thread 0 runs the sequential-c fp32 chain from LDS (branchless fma:
// fma(x,w,acc) with x in {0,1} == conditional __fadd_rn, single rounding).
// ---------------------------------------------------------------------------
__global__ __launch_bounds__(256) void k_fixup(
    const unsigned char* __restrict__ xs,
    const float* __restrict__ qw, const float* __restrict__ kw, const float* __restrict__ vw,
    const float* __restrict__ qg, const float* __restrict__ qb,
    const float* __restrict__ qm, const float* __restrict__ qv,
    const float* __restrict__ kg_, const float* __restrict__ kb_,
    const float* __restrict__ km_, const float* __restrict__ kv_,
    const float* __restrict__ vg, const float* __restrict__ vb,
    const float* __restrict__ vm_, const float* __restrict__ vv_,
    unsigned char* __restrict__ qs, unsigned char* __restrict__ ks,
    unsigned char* __restrict__ vs,
    const unsigned* __restrict__ cnt, const unsigned* __restrict__ list) {
    __shared__ __align__(16) float sw[CC];
    __shared__ __align__(16) unsigned char sx[TT][CC];
    unsigned nfl = *cnt;
    if (nfl > FCAP) nfl = FCAP;
    for (unsigned i = blockIdx.x; i < nfl; i += gridDim.x) {
        unsigned e = list[i];
        int mat = e >> 22, b_ = (e >> 17) & 31, o = (e >> 8) & 511, n = e & 255;
        const float* wbase = (mat == 0) ? qw : (mat == 1) ? kw : vw;
        const float* wrow = wbase + (size_t)o * CC;
        // stage weight row (coalesced f32) and 4 spike rows (u64)
        for (int c = threadIdx.x; c < CC; c += 256) sw[c] = wrow[c];
        if (threadIdx.x < TT * (CC / 8)) {
            int t = threadIdx.x / (CC / 8), q = threadIdx.x % (CC / 8);
            *(u64*)&sx[t][q * 8] =
                *(const u64*)&xs[((size_t)((t * BB + b_) * NN) + n) * CC + q * 8];
        }
        __syncthreads();
        if (threadIdx.x == 0) {
            const float* G = (mat == 0) ? qg : (mat == 1) ? kg_ : vg;
            const float* Bb = (mat == 0) ? qb : (mat == 1) ? kb_ : vb;
            const float* M = (mat == 0) ? qm : (mat == 1) ? km_ : vm_;
            const float* V = (mat == 0) ? qv : (mat == 1) ? kv_ : vv_;
            unsigned char* S = (mat == 0) ? qs : (mat == 1) ? ks : vs;
            const float inv = __fdiv_rn(G[o], __fsqrt_rn(__fadd_rn(V[o], 1e-5f)));
            const float mu = M[o], be = Bb[o];
            float vmem = 0.f;
            for (int t = 0; t < TT; ++t) {
                float acc = 0.f;
                for (int c = 0; c < CC; ++c)
                    acc = __fmaf_rn((float)sx[t][c], sw[c], acc);
                float y = __fadd_rn(__fmul_rn(__fsub_rn(acc, mu), inv), be);
                vmem = __fadd_rn(vmem, __fmul_rn(__fsub_rn(y, vmem), 0.5f));
                int s = (vmem >= 0.5f);
                S[((size_t)((t * BB + b_) * NN) + n) * CC + o] = (unsigned char)s;
                if (s) vmem = 0.f;
            }
        }
        __syncthreads();
    }
}

// ---------------------------------------------------------------------------
// Kernel 3: v spikes [t,b,n,c] u8 -> f32 out [t,b,h,n,d]
// ---------------------------------------------------------------------------
__global__ __launch_bounds__(256) void k_vout(const unsigned char* __restrict__ vs,
                                              float* __restrict__ vout) {
    int e = blockIdx.x * 256 + threadIdx.x;
    int d4 = e % 12;
    int r = e / 12;
    int n = r & 255;
    r >>= 8;
    int h = r & 7;
    int tb = r >> 3;
    uchar4 u = *(const uchar4*)&vs[((size_t)tb * NN + n) * CC + h * HD + d4 * 4];
    float4 o = {(float)u.x, (float)u.y, (float)u.z, (float)u.w};
    *(float4*)&vout[(((size_t)tb * HEADS + h) * NN + n) * HD + d4 * 4] = o;
}

// ---------------------------------------------------------------------------
// Kernel 4: kvsum[t,b,c] = sum_n k*v  (exact integer)
// ---------------------------------------------------------------------------
__global__ __launch_bounds__(256) void k_kvsum(const unsigned char* __restrict__ ks,
                                               const unsigned char* __restrict__ vs,
                                               int* __restrict__ kvsum) {
    __shared__ int P[5][CC];
    const int tb = blockIdx.x, tid = threadIdx.x;
    if (tid < 240) {
        int c8 = tid % 48, sl = tid / 48;
        int a[8] = {0, 0, 0, 0, 0, 0, 0, 0};
        for (int n = sl; n < NN; n += 5) {
            u64 kk = *(const u64*)&ks[((size_t)tb * NN + n) * CC + c8 * 8];
            u64 vvv = *(const u64*)&vs[((size_t)tb * NN + n) * CC + c8 * 8];
            u64 u = kk & vvv;
#pragma unroll
            for (int j = 0; j < 8; ++j) a[j] += (int)((u >> (8 * j)) & 1);
        }
#pragma unroll
        for (int j = 0; j < 8; ++j) P[sl][c8 * 8 + j] = a[j];
    }
    __syncthreads();
    for (int c = tid; c < CC; c += 256) {
        kvsum[(size_t)tb * CC + c] = P[0][c] + P[1][c] + P[2][c] + P[3][c] + P[4][c];
    }
}

// ---------------------------------------------------------------------------
// Kernel 5: talking heads + LIF, fp32 np-order
// ---------------------------------------------------------------------------
__global__ __launch_bounds__(384) void k_thlif(const int* __restrict__ kvsum,
                                               const float* __restrict__ th,
                                               unsigned char* __restrict__ kvm) {
    __shared__ int kv0[TT][CC];
    const int b_ = blockIdx.x, c = threadIdx.x;
#pragma unroll
    for (int t = 0; t < TT; ++t) kv0[t][c] = kvsum[(size_t)(t * BB + b_) * CC + c];
    __syncthreads();
    const int ho = c / HD, d = c % HD;
    float vmem = 0.f;
#pragma unroll
    for (int t = 0; t < TT; ++t) {
        float s = 0.f;
#pragma unroll
        for (int h = 0; h < HEADS; ++h)
            s = __fadd_rn(s, __fmul_rn(th[ho * HEADS + h], (float)kv0[t][h * HD + d]));
        vmem = __fadd_rn(vmem, __fmul_rn(__fsub_rn(s, vmem), 0.5f));
        int sp = (vmem >= 0.5f);
        kvm[(size_t)(t * BB + b_) * CC + c] = (unsigned char)sp;
        if (sp) vmem = 0.f;
    }
}

// ---------------------------------------------------------------------------
// Kernel 6: proj GEMM (3-plane i8 on q & kvmask); fp64 epilogue:
// +bias, BN, +identity -> f32 out [t,b,c,n]  (real-valued; no decisions)
// ---------------------------------------------------------------------------
__global__ __launch_bounds__(256, 2) void k_proj_i8(
    const unsigned char* __restrict__ qs, const unsigned char* __restrict__ kvm,
    const signed char* __restrict__ wq, const float* __restrict__ pbias,
    const float* __restrict__ gg, const float* __restrict__ bbp,
    const float* __restrict__ mmp, const float* __restrict__ vvp,
    const float* __restrict__ xin, float* __restrict__ out) {
    __shared__ LdsU L;
    const int b_ = blockIdx.x, ob = blockIdx.y * 64, nb = blockIdx.z * 32;
    const int tid = threadIdx.x, lane = tid & 63, w = tid >> 6;
    const int lo16 = lane & 15, hi4 = lane >> 4;

    i32x4 acc[3][4][2];
#pragma unroll
    for (int p = 0; p < 3; ++p)
#pragma unroll
        for (int t = 0; t < 4; ++t)
#pragma unroll
            for (int nf = 0; nf < 2; ++nf) acc[p][t][nf] = (i32x4){0, 0, 0, 0};

    for (int k0 = 0; k0 < CC; k0 += 32) {
#pragma unroll
        for (int pl = 0; pl < 3; ++pl) {
            int o = tid >> 2, kg = tid & 3;
            u64 v = *(const u64*)&wq[(size_t)pl * CCC + (size_t)(ob + o) * CC + k0 + kg * 8];
            *(u64*)&L.st.W8[pl][o][kg * 8] = v;
        }
#pragma unroll
        for (int i = 0; i < 2; ++i) {
            int e = tid + 256 * i;
            int t = e >> 7, rem = e & 127, n = rem >> 2, kg = rem & 3;
            u64 uq = *(const u64*)&qs[((size_t)((t * BB + b_) * NN) + nb + n) * CC + k0 + kg * 8];
            u64 um = *(const u64*)&kvm[(size_t)(t * BB + b_) * CC + k0 + kg * 8];
            *(u64*)&L.st.S8[t][n][kg * 8] = uq & um;
        }
        __syncthreads();
        u64 af0 = *(const u64*)&L.st.W8[0][w * 16 + lo16][hi4 * 8];
        u64 af1 = *(const u64*)&L.st.W8[1][w * 16 + lo16][hi4 * 8];
        u64 af2 = *(const u64*)&L.st.W8[2][w * 16 + lo16][hi4 * 8];
#pragma unroll
        for (int t = 0; t < 4; ++t)
#pragma unroll
            for (int nf = 0; nf < 2; ++nf) {
                u64 bfr = *(const u64*)&L.st.S8[t][nf * 16 + lo16][hi4 * 8];
                acc[0][t][nf] = __builtin_amdgcn_mfma_i32_16x16x32_i8((long)af0, (long)bfr, acc[0][t][nf], 0, 0, 0);
                acc[1][t][nf] = __builtin_amdgcn_mfma_i32_16x16x32_i8((long)af1, (long)bfr, acc[1][t][nf], 0, 0, 0);
                acc[2][t][nf] = __builtin_amdgcn_mfma_i32_16x16x32_i8((long)af2, (long)bfr, acc[2][t][nf], 0, 0, 0);
            }
        __syncthreads();
    }

#pragma unroll
    for (int r = 0; r < 4; ++r) {
        const int o = ob + w * 16 + hi4 * 4 + r;
        const double inv = (double)gg[o] / sqrt((double)vvp[o] + 1e-5);
        const double mu = (double)mmp[o], be = (double)bbp[o], pb = (double)pbias[o];
#pragma unroll
        for (int nf = 0; nf < 2; ++nf) {
#pragma unroll
            for (int t = 0; t < 4; ++t) {
                long long N = (long long)acc[0][t][nf][r] + 256LL * acc[1][t][nf][r]
                            + 65536LL * acc[2][t][nf][r];
                double tot = (double)N * 0x1p-23;
                size_t idx = ((size_t)((t * BB + b_) * CC) + o) * NN + nb + nf * 16 + lo16;
                double y = (tot + pb - mu) * inv + be;
                out[idx] = (float)(y + (double)xin[idx]);
            }
        }
    }
}

// ---------------------------------------------------------------------------
extern "C" void kernel_launch(void* const* d_in, const int* in_sizes, int n_in,
                              void* d_out, int out_size, void* d_ws, size_t ws_size,
                              hipStream_t stream) {
    const float* x    = (const float*)d_in[0];
    const float* q_w  = (const float*)d_in[1];
    const float* k_w  = (const float*)d_in[2];
    const float* v_w  = (const float*)d_in[3];
    const float* q_g  = (const float*)d_in[4];
    const float* q_b  = (const float*)d_in[5];
    const float* q_m  = (const float*)d_in[6];
    const float* q_v  = (const float*)d_in[7];
    const float* k_g  = (const float*)d_in[8];
    const float* k_b  = (const float*)d_in[9];
    const float* k_m  = (const float*)d_in[10];
    const float* k_v  = (const float*)d_in[11];
    const float* v_g  = (const float*)d_in[12];
    const float* v_b  = (const float*)d_in[13];
    const float* v_m  = (const float*)d_in[14];
    const float* v_v  = (const float*)d_in[15];
    const float* p_g  = (const float*)d_in[16];
    const float* p_b  = (const float*)d_in[17];
    const float* p_m  = (const float*)d_in[18];
    const float* p_v  = (const float*)d_in[19];
    const float* th_w = (const float*)d_in[20];
    const float* pr_w = (const float*)d_in[21];
    const float* pr_b = (const float*)d_in[22];

    float* out  = (float*)d_out;
    float* vout = out + (size_t)TBCN;

    unsigned char* ws  = (unsigned char*)d_ws;
    unsigned char* xs  = ws;
    unsigned char* qs  = ws + (size_t)TBCN;
    unsigned char* ks2 = ws + (size_t)2 * TBCN;
    unsigned char* vs2 = ws + (size_t)3 * TBCN;
    signed char* wq    = (signed char*)(ws + (size_t)4 * TBCN);          // 4 mats * 3*CCC
    int* kvsum         = (int*)(ws + (size_t)4 * TBCN + 12ull * CCC);
    unsigned char* kvm = (unsigned char*)(kvsum + TT * BB * CC);
    unsigned* fcnt     = (unsigned*)(kvm + (size_t)TT * BB * CC + 64);
    unsigned* flist    = fcnt + 16;

    k_wsplit<<<(4 * CCC) / 256, 256, 0, stream>>>(q_w, k_w, v_w, pr_w, wq, fcnt);
    k_lif_x<<<dim3(BB, CC / 64, NN / 64), 256, 0, stream>>>(x, xs);

    dim3 gg(BB, CC / 64, NN / 32);
    k_branch_i8<<<gg, 256, 0, stream>>>(xs, wq + 0ull * 3 * CCC, q_g, q_b, q_m, q_v, qs, 0, fcnt, flist);
    k_branch_i8<<<gg, 256, 0, stream>>>(xs, wq + 1ull * 3 * CCC, k_g, k_b, k_m, k_v, ks2, 1, fcnt, flist);
    k_branch_i8<<<gg, 256, 0, stream>>>(xs, wq + 2ull * 3 * CCC, v_g, v_b, v_m, v_v, vs2, 2, fcnt, flist);

    k_fixup<<<1024, 256, 0, stream>>>(xs, q_w, k_w, v_w,
                                      q_g, q_b, q_m, q_v,
                                      k_g, k_b, k_m, k_v,
                                      v_g, v_b, v_m, v_v,
                                      qs, ks2, vs2, fcnt, flist);

    k_vout<<<(TBCN / 4) / 256, 256, 0, stream>>>(vs2, vout);
    k_kvsum<<<TT * BB, 256, 0, stream>>>(ks2, vs2, kvsum);
    k_thlif<<<BB, CC, 0, stream>>>(kvsum, th_w, kvm);

    k_proj_i8<<<gg, 256, 0, stream>>>(qs, kvm, wq + 3ull * 3 * CCC, pr_b,
                                      p_g, p_b, p_m, p_v, x, out);
}

// Round 8
// 225.339 us; speedup vs baseline: 3.1714x; 1.4997x over previous
//
#include <hip/hip_runtime.h>
#include <math.h>

typedef int i32x4 __attribute__((ext_vector_type(4)));
typedef unsigned long long u64;

constexpr int TT = 4;
constexpr int BB = 32;
constexpr int CC = 384;
constexpr int NN = 256;
constexpr int HEADS = 8;
constexpr int HD = 48;
constexpr int BCN = BB * CC * NN;
constexpr int TBCN = TT * BCN;          // 12,582,912
constexpr int CCC = CC * CC;            // 147,456
constexpr float MARGIN = 1e-4f;         // LIF margin triggering np-exact recompute
                                        // (main-path vs np deviation << 1e-4)
constexpr unsigned FCAP = 262144;       // flag list capacity

// ---------------------------------------------------------------------------
// LDS overlay (tile: 64 o x 32 n x 4 t, 3 digit planes)
// ---------------------------------------------------------------------------
union LdsU {
    struct {
        unsigned char W8[3][64][40];   // weight digit planes [pl][o][k] (+8B pad)
        unsigned char S8[4][32][40];   // spikes [t][n][k] (+8B pad)
    } st;
    unsigned char R[4][32][64];        // spike repack [t][n][c]
};

// ---------------------------------------------------------------------------
// Kernel 0: quantize fp32 weights -> 3 signed-i8 digit planes of round(w*2^23)
// Also zeroes the flag counter.
// ---------------------------------------------------------------------------
__global__ __launch_bounds__(256) void k_wsplit(
    const float* __restrict__ qw, const float* __restrict__ kw,
    const float* __restrict__ vw, const float* __restrict__ pw,
    signed char* __restrict__ wq, unsigned* __restrict__ cnt) {
    if (blockIdx.x == 0 && threadIdx.x == 0) *cnt = 0u;
    int idx = blockIdx.x * 256 + threadIdx.x;     // 4*CCC total
    int mat = idx / CCC, r = idx % CCC;
    const float* src = (mat == 0) ? qw : (mat == 1) ? kw : (mat == 2) ? vw : pw;
    double w = (double)src[r];
    long long W = llround(w * 8388608.0);         // w * 2^23 (|w| < 0.99)
    signed char d0 = (signed char)(W & 0xff); W = (W - d0) >> 8;
    signed char d1 = (signed char)(W & 0xff); W = (W - d1) >> 8;
    signed char d2 = (signed char)W;              // |d2| <= 64 for |w|<1
    size_t base = (size_t)mat * 3 * CCC;
    wq[base + 0 * CCC + r] = d0;
    wq[base + 1 * CCC + r] = d1;
    wq[base + 2 * CCC + r] = d2;
}

// ---------------------------------------------------------------------------
// Kernel 1: shortcut LIF on x [t,b,c,n] -> u8 spikes xs in [t,b,n,c]
// fp32 ops in exact np order.
// ---------------------------------------------------------------------------
__global__ __launch_bounds__(256) void k_lif_x(const float* __restrict__ x,
                                               unsigned char* __restrict__ xs) {
    __shared__ unsigned char sL[4][64][64];
    const int b_ = blockIdx.x, c0 = blockIdx.y * 64, n0 = blockIdx.z * 64;
    const int tid = threadIdx.x;

    float vm[4][4];
#pragma unroll
    for (int a = 0; a < 4; ++a)
#pragma unroll
        for (int j = 0; j < 4; ++j) vm[a][j] = 0.f;

#pragma unroll
    for (int t = 0; t < TT; ++t) {
#pragma unroll
        for (int a = 0; a < 4; ++a) {
            int idx = tid + 256 * a;
            int ci = idx >> 4, nj4 = idx & 15;
            float4 xv = *(const float4*)&x[((size_t)((t * BB + b_) * CC) + c0 + ci) * NN + n0 + nj4 * 4];
            float xa[4] = {xv.x, xv.y, xv.z, xv.w};
#pragma unroll
            for (int j = 0; j < 4; ++j) {
                vm[a][j] = __fadd_rn(vm[a][j], __fmul_rn(__fsub_rn(xa[j], vm[a][j]), 0.5f));
                int s = (vm[a][j] >= 0.5f);
                sL[t][nj4 * 4 + j][ci] = (unsigned char)s;
                if (s) vm[a][j] = 0.f;
            }
        }
    }
    __syncthreads();
#pragma unroll
    for (int i = 0; i < 16; ++i) {
        int s = tid + 256 * i;
        int c4 = s & 15, n = (s >> 4) & 63, t = s >> 10;
        *(uchar4*)&xs[((size_t)((t * BB + b_) * NN) + n0 + n) * CC + c0 + c4 * 4] =
            *(const uchar4*)&sL[t][n][c4 * 4];
    }
}

// ---------------------------------------------------------------------------
// Kernel 2: branch GEMM, 3-plane i8 MFMA + fp32(np-order) BN+LIF -> u8 [t,b,n,c]
// Near-threshold trajectories flagged for np-exact recompute.
// ---------------------------------------------------------------------------
__global__ __launch_bounds__(256, 2) void k_branch_i8(
    const unsigned char* __restrict__ xs, const signed char* __restrict__ wq,
    const float* __restrict__ gg, const float* __restrict__ bbp,
    const float* __restrict__ mmp, const float* __restrict__ vvp,
    unsigned char* __restrict__ spk, int mat,
    unsigned* __restrict__ cnt, unsigned* __restrict__ list) {
    __shared__ LdsU L;
    const int b_ = blockIdx.x, ob = blockIdx.y * 64, nb = blockIdx.z * 32;
    const int tid = threadIdx.x, lane = tid & 63, w = tid >> 6;
    const int lo16 = lane & 15, hi4 = lane >> 4;

    i32x4 acc[3][4][2];
#pragma unroll
    for (int p = 0; p < 3; ++p)
#pragma unroll
        for (int t = 0; t < 4; ++t)
#pragma unroll
            for (int nf = 0; nf < 2; ++nf) acc[p][t][nf] = (i32x4){0, 0, 0, 0};

    for (int k0 = 0; k0 < CC; k0 += 32) {
#pragma unroll
        for (int pl = 0; pl < 3; ++pl) {   // stage 3 weight digit planes [64][32]
            int o = tid >> 2, kg = tid & 3;
            u64 v = *(const u64*)&wq[(size_t)pl * CCC + (size_t)(ob + o) * CC + k0 + kg * 8];
            *(u64*)&L.st.W8[pl][o][kg * 8] = v;
        }
#pragma unroll
        for (int i = 0; i < 2; ++i) {      // stage spikes [4][32][32]
            int e = tid + 256 * i;
            int t = e >> 7, rem = e & 127, n = rem >> 2, kg = rem & 3;
            u64 v = *(const u64*)&xs[((size_t)((t * BB + b_) * NN) + nb + n) * CC + k0 + kg * 8];
            *(u64*)&L.st.S8[t][n][kg * 8] = v;
        }
        __syncthreads();
        u64 af0 = *(const u64*)&L.st.W8[0][w * 16 + lo16][hi4 * 8];
        u64 af1 = *(const u64*)&L.st.W8[1][w * 16 + lo16][hi4 * 8];
        u64 af2 = *(const u64*)&L.st.W8[2][w * 16 + lo16][hi4 * 8];
#pragma unroll
        for (int t = 0; t < 4; ++t)
#pragma unroll
            for (int nf = 0; nf < 2; ++nf) {
                u64 bfr = *(const u64*)&L.st.S8[t][nf * 16 + lo16][hi4 * 8];
                acc[0][t][nf] = __builtin_amdgcn_mfma_i32_16x16x32_i8((long)af0, (long)bfr, acc[0][t][nf], 0, 0, 0);
                acc[1][t][nf] = __builtin_amdgcn_mfma_i32_16x16x32_i8((long)af1, (long)bfr, acc[1][t][nf], 0, 0, 0);
                acc[2][t][nf] = __builtin_amdgcn_mfma_i32_16x16x32_i8((long)af2, (long)bfr, acc[2][t][nf], 0, 0, 0);
            }
        __syncthreads();
    }

    // epilogue: fp32 np-order BN + LIF, margin flagging, spikes into LDS repack
#pragma unroll
    for (int r = 0; r < 4; ++r) {
        const int o = ob + w * 16 + hi4 * 4 + r;
        const float inv = __fdiv_rn(gg[o], __fsqrt_rn(__fadd_rn(vvp[o], 1e-5f)));
        const float mu = mmp[o], be = bbp[o];
#pragma unroll
        for (int nf = 0; nf < 2; ++nf) {
            float vmem = 0.f, mg = 1e9f;
#pragma unroll
            for (int t = 0; t < 4; ++t) {
                long long N = (long long)acc[0][t][nf][r] + 256LL * acc[1][t][nf][r]
                            + 65536LL * acc[2][t][nf][r];
                float dotf = (float)((double)N * 0x1p-23);
                float y = __fadd_rn(__fmul_rn(__fsub_rn(dotf, mu), inv), be);
                vmem = __fadd_rn(vmem, __fmul_rn(__fsub_rn(y, vmem), 0.5f));
                mg = fminf(mg, fabsf(__fsub_rn(vmem, 0.5f)));
                int s = (vmem >= 0.5f);
                L.R[t][nf * 16 + lo16][w * 16 + hi4 * 4 + r] = (unsigned char)s;
                if (s) vmem = 0.f;
            }
            if (mg < MARGIN) {
                unsigned idx = atomicAdd(cnt, 1u);
                int n = nb + nf * 16 + lo16;
                if (idx < FCAP) list[idx] = ((unsigned)mat << 22) | ((unsigned)b_ << 17) |
                                            ((unsigned)o << 8) | (unsigned)n;
            }
        }
    }
    __syncthreads();
#pragma unroll
    for (int i = 0; i < 8; ++i) {
        int e = tid + 256 * i;
        int c4 = e & 15, n = (e >> 4) & 31, t = e >> 9;
        *(uchar4*)&spk[((size_t)((t * BB + b_) * NN) + nb + n) * CC + ob + c4 * 4] =
            *(const uchar4*)&L.R[t][n][c4 * 4];
    }
}

// ---------------------------------------------------------------------------
// Kernel 2b: np-exact fixup of flagged trajectories.
// One block per item (grid-stride). 256 threads stage wrow + 4 xs rows into
// LDS; then 4 THREADS compute the 4 independent per-t dots in parallel (each
// a sequential-c fp32 fma chain, np order); thread 0 runs the 4-step LIF.
// ---------------------------------------------------------------------------
__global__ __launch_bounds__(256) void k_fixup(
    const unsigned char* __restrict__ xs,
    const float* __restrict__ qw, const float* __restrict__ kw, const float* __restrict__ vw,
    const float* __restrict__ qg, const float* __restrict__ qb,
    const float* __restrict__ qm, const float* __restrict__ qv,
    const float* __restrict__ kg_, const float* __restrict__ kb_,
    const float* __restrict__ km_, const float* __restrict__ kv_,
    const float* __restrict__ vg, const float* __restrict__ vb,
    const float* __restrict__ vm_, const float* __restrict__ vv_,
    unsigned char* __restrict__ qs, unsigned char* __restrict__ ks,
    unsigned char* __restrict__ vs,
    const unsigned* __restrict__ cnt, const unsigned* __restrict__ list) {
    __shared__ __align__(16) float sw[CC];
    __shared__ __align__(16) unsigned char sx[TT][CC];
    __shared__ float dots[TT];
    unsigned nfl = *cnt;
    if (nfl > FCAP) nfl = FCAP;
    for (unsigned i = blockIdx.x; i < nfl; i += gridDim.x) {
        unsigned e = list[i];
        int mat = e >> 22, b_ = (e >> 17) & 31, o = (e >> 8) & 511, n = e & 255;
        const float* wbase = (mat == 0) ? qw : (mat == 1) ? kw : vw;
        const float* wrow = wbase + (size_t)o * CC;
        // stage weight row (coalesced f32) and 4 spike rows (u64)
        for (int c = threadIdx.x; c < CC; c += 256) sw[c] = wrow[c];
        if (threadIdx.x < TT * (CC / 8)) {
            int t = threadIdx.x / (CC / 8), q = threadIdx.x % (CC / 8);
            *(u64*)&sx[t][q * 8] =
                *(const u64*)&xs[((size_t)((t * BB + b_) * NN) + n) * CC + q * 8];
        }
        __syncthreads();
        if (threadIdx.x < TT) {            // 4 parallel np-order dot chains
            int t = threadIdx.x;
            float acc = 0.f;
            for (int c = 0; c < CC; ++c)
                acc = __fmaf_rn((float)sx[t][c], sw[c], acc);
            dots[t] = acc;
        }
        __syncthreads();
        if (threadIdx.x == 0) {
            const float* G = (mat == 0) ? qg : (mat == 1) ? kg_ : vg;
            const float* Bb = (mat == 0) ? qb : (mat == 1) ? kb_ : vb;
            const float* M = (mat == 0) ? qm : (mat == 1) ? km_ : vm_;
            const float* V = (mat == 0) ? qv : (mat == 1) ? kv_ : vv_;
            unsigned char* S = (mat == 0) ? qs : (mat == 1) ? ks : vs;
            const float inv = __fdiv_rn(G[o], __fsqrt_rn(__fadd_rn(V[o], 1e-5f)));
            const float mu = M[o], be = Bb[o];
            float vmem = 0.f;
            for (int t = 0; t < TT; ++t) {
                float y = __fadd_rn(__fmul_rn(__fsub_rn(dots[t], mu), inv), be);
                vmem = __fadd_rn(vmem, __fmul_rn(__fsub_rn(y, vmem), 0.5f));
                int s = (vmem >= 0.5f);
                S[((size_t)((t * BB + b_) * NN) + n) * CC + o] = (unsigned char)s;
                if (s) vmem = 0.f;
            }
        }
        __syncthreads();
    }
}

// ---------------------------------------------------------------------------
// Kernel 3: v spikes [t,b,n,c] u8 -> f32 out [t,b,h,n,d]
// ---------------------------------------------------------------------------
__global__ __launch_bounds__(256) void k_vout(const unsigned char* __restrict__ vs,
                                              float* __restrict__ vout) {
    int e = blockIdx.x * 256 + threadIdx.x;
    int d4 = e % 12;
    int r = e / 12;
    int n = r & 255;
    r >>= 8;
    int h = r & 7;
    int tb = r >> 3;
    uchar4 u = *(const uchar4*)&vs[((size_t)tb * NN + n) * CC + h * HD + d4 * 4];
    float4 o = {(float)u.x, (float)u.y, (float)u.z, (float)u.w};
    *(float4*)&vout[(((size_t)tb * HEADS + h) * NN + n) * HD + d4 * 4] = o;
}

// ---------------------------------------------------------------------------
// Kernel 4: kvsum[t,b,c] = sum_n k*v  (exact integer)
// ---------------------------------------------------------------------------
__global__ __launch_bounds__(256) void k_kvsum(const unsigned char* __restrict__ ks,
                                               const unsigned char* __restrict__ vs,
                                               int* __restrict__ kvsum) {
    __shared__ int P[5][CC];
    const int tb = blockIdx.x, tid = threadIdx.x;
    if (tid < 240) {
        int c8 = tid % 48, sl = tid / 48;
        int a[8] = {0, 0, 0, 0, 0, 0, 0, 0};
        for (int n = sl; n < NN; n += 5) {
            u64 kk = *(const u64*)&ks[((size_t)tb * NN + n) * CC + c8 * 8];
            u64 vvv = *(const u64*)&vs[((size_t)tb * NN + n) * CC + c8 * 8];
            u64 u = kk & vvv;
#pragma unroll
            for (int j = 0; j < 8; ++j) a[j] += (int)((u >> (8 * j)) & 1);
        }
#pragma unroll
        for (int j = 0; j < 8; ++j) P[sl][c8 * 8 + j] = a[j];
    }
    __syncthreads();
    for (int c = tid; c < CC; c += 256) {
        kvsum[(size_t)tb * CC + c] = P[0][c] + P[1][c] + P[2][c] + P[3][c] + P[4][c];
    }
}

// ---------------------------------------------------------------------------
// Kernel 5: talking heads + LIF, fp32 np-order
// ---------------------------------------------------------------------------
__global__ __launch_bounds__(384) void k_thlif(const int* __restrict__ kvsum,
                                               const float* __restrict__ th,
                                               unsigned char* __restrict__ kvm) {
    __shared__ int kv0[TT][CC];
    const int b_ = blockIdx.x, c = threadIdx.x;
#pragma unroll
    for (int t = 0; t < TT; ++t) kv0[t][c] = kvsum[(size_t)(t * BB + b_) * CC + c];
    __syncthreads();
    const int ho = c / HD, d = c % HD;
    float vmem = 0.f;
#pragma unroll
    for (int t = 0; t < TT; ++t) {
        float s = 0.f;
#pragma unroll
        for (int h = 0; h < HEADS; ++h)
            s = __fadd_rn(s, __fmul_rn(th[ho * HEADS + h], (float)kv0[t][h * HD + d]));
        vmem = __fadd_rn(vmem, __fmul_rn(__fsub_rn(s, vmem), 0.5f));
        int sp = (vmem >= 0.5f);
        kvm[(size_t)(t * BB + b_) * CC + c] = (unsigned char)sp;
        if (sp) vmem = 0.f;
    }
}

// ---------------------------------------------------------------------------
// Kernel 6: proj GEMM (3-plane i8 on q & kvmask); fp64 epilogue:
// +bias, BN, +identity -> f32 out [t,b,c,n]  (real-valued; no decisions)
// ---------------------------------------------------------------------------
__global__ __launch_bounds__(256, 2) void k_proj_i8(
    const unsigned char* __restrict__ qs, const unsigned char* __restrict__ kvm,
    const signed char* __restrict__ wq, const float* __restrict__ pbias,
    const float* __restrict__ gg, const float* __restrict__ bbp,
    const float* __restrict__ mmp, const float* __restrict__ vvp,
    const float* __restrict__ xin, float* __restrict__ out) {
    __shared__ LdsU L;
    const int b_ = blockIdx.x, ob = blockIdx.y * 64, nb = blockIdx.z * 32;
    const int tid = threadIdx.x, lane = tid & 63, w = tid >> 6;
    const int lo16 = lane & 15, hi4 = lane >> 4;

    i32x4 acc[3][4][2];
#pragma unroll
    for (int p = 0; p < 3; ++p)
#pragma unroll
        for (int t = 0; t < 4; ++t)
#pragma unroll
            for (int nf = 0; nf < 2; ++nf) acc[p][t][nf] = (i32x4){0, 0, 0, 0};

    for (int k0 = 0; k0 < CC; k0 += 32) {
#pragma unroll
        for (int pl = 0; pl < 3; ++pl) {
            int o = tid >> 2, kg = tid & 3;
            u64 v = *(const u64*)&wq[(size_t)pl * CCC + (size_t)(ob + o) * CC + k0 + kg * 8];
            *(u64*)&L.st.W8[pl][o][kg * 8] = v;
        }
#pragma unroll
        for (int i = 0; i < 2; ++i) {
            int e = tid + 256 * i;
            int t = e >> 7, rem = e & 127, n = rem >> 2, kg = rem & 3;
            u64 uq = *(const u64*)&qs[((size_t)((t * BB + b_) * NN) + nb + n) * CC + k0 + kg * 8];
            u64 um = *(const u64*)&kvm[(size_t)(t * BB + b_) * CC + k0 + kg * 8];
            *(u64*)&L.st.S8[t][n][kg * 8] = uq & um;
        }
        __syncthreads();
        u64 af0 = *(const u64*)&L.st.W8[0][w * 16 + lo16][hi4 * 8];
        u64 af1 = *(const u64*)&L.st.W8[1][w * 16 + lo16][hi4 * 8];
        u64 af2 = *(const u64*)&L.st.W8[2][w * 16 + lo16][hi4 * 8];
#pragma unroll
        for (int t = 0; t < 4; ++t)
#pragma unroll
            for (int nf = 0; nf < 2; ++nf) {
                u64 bfr = *(const u64*)&L.st.S8[t][nf * 16 + lo16][hi4 * 8];
                acc[0][t][nf] = __builtin_amdgcn_mfma_i32_16x16x32_i8((long)af0, (long)bfr, acc[0][t][nf], 0, 0, 0);
                acc[1][t][nf] = __builtin_amdgcn_mfma_i32_16x16x32_i8((long)af1, (long)bfr, acc[1][t][nf], 0, 0, 0);
                acc[2][t][nf] = __builtin_amdgcn_mfma_i32_16x16x32_i8((long)af2, (long)bfr, acc[2][t][nf], 0, 0, 0);
            }
        __syncthreads();
    }

#pragma unroll
    for (int r = 0; r < 4; ++r) {
        const int o = ob + w * 16 + hi4 * 4 + r;
        const double inv = (double)gg[o] / sqrt((double)vvp[o] + 1e-5);
        const double mu = (double)mmp[o], be = (double)bbp[o], pb = (double)pbias[o];
#pragma unroll
        for (int nf = 0; nf < 2; ++nf) {
#pragma unroll
            for (int t = 0; t < 4; ++t) {
                long long N = (long long)acc[0][t][nf][r] + 256LL * acc[1][t][nf][r]
                            + 65536LL * acc[2][t][nf][r];
                double tot = (double)N * 0x1p-23;
                size_t idx = ((size_t)((t * BB + b_) * CC) + o) * NN + nb + nf * 16 + lo16;
                double y = (tot + pb - mu) * inv + be;
                out[idx] = (float)(y + (double)xin[idx]);
            }
        }
    }
}

// ---------------------------------------------------------------------------
extern "C" void kernel_launch(void* const* d_in, const int* in_sizes, int n_in,
                              void* d_out, int out_size, void* d_ws, size_t ws_size,
                              hipStream_t stream) {
    const float* x    = (const float*)d_in[0];
    const float* q_w  = (const float*)d_in[1];
    const float* k_w  = (const float*)d_in[2];
    const float* v_w  = (const float*)d_in[3];
    const float* q_g  = (const float*)d_in[4];
    const float* q_b  = (const float*)d_in[5];
    const float* q_m  = (const float*)d_in[6];
    const float* q_v  = (const float*)d_in[7];
    const float* k_g  = (const float*)d_in[8];
    const float* k_b  = (const float*)d_in[9];
    const float* k_m  = (const float*)d_in[10];
    const float* k_v  = (const float*)d_in[11];
    const float* v_g  = (const float*)d_in[12];
    const float* v_b  = (const float*)d_in[13];
    const float* v_m  = (const float*)d_in[14];
    const float* v_v  = (const float*)d_in[15];
    const float* p_g  = (const float*)d_in[16];
    const float* p_b  = (const float*)d_in[17];
    const float* p_m  = (const float*)d_in[18];
    const float* p_v  = (const float*)d_in[19];
    const float* th_w = (const float*)d_in[20];
    const float* pr_w = (const float*)d_in[21];
    const float* pr_b = (const float*)d_in[22];

    float* out  = (float*)d_out;
    float* vout = out + (size_t)TBCN;

    unsigned char* ws  = (unsigned char*)d_ws;
    unsigned char* xs  = ws;
    unsigned char* qs  = ws + (size_t)TBCN;
    unsigned char* ks2 = ws + (size_t)2 * TBCN;
    unsigned char* vs2 = ws + (size_t)3 * TBCN;
    signed char* wq    = (signed char*)(ws + (size_t)4 * TBCN);          // 4 mats * 3*CCC
    int* kvsum         = (int*)(ws + (size_t)4 * TBCN + 12ull * CCC);
    unsigned char* kvm = (unsigned char*)(kvsum + TT * BB * CC);
    unsigned* fcnt     = (unsigned*)(kvm + (size_t)TT * BB * CC + 64);
    unsigned* flist    = fcnt + 16;

    k_wsplit<<<(4 * CCC) / 256, 256, 0, stream>>>(q_w, k_w, v_w, pr_w, wq, fcnt);
    k_lif_x<<<dim3(BB, CC / 64, NN / 64), 256, 0, stream>>>(x, xs);

    dim3 gg(BB, CC / 64, NN / 32);
    k_branch_i8<<<gg, 256, 0, stream>>>(xs, wq + 0ull * 3 * CCC, q_g, q_b, q_m, q_v, qs, 0, fcnt, flist);
    k_branch_i8<<<gg, 256, 0, stream>>>(xs, wq + 1ull * 3 * CCC, k_g, k_b, k_m, k_v, ks2, 1, fcnt, flist);
    k_branch_i8<<<gg, 256, 0, stream>>>(xs, wq + 2ull * 3 * CCC, v_g, v_b, v_m, v_v, vs2, 2, fcnt, flist);

    k_fixup<<<2048, 256, 0, stream>>>(xs, q_w, k_w, v_w,
                                      q_g, q_b, q_m, q_v,
                                      k_g, k_b, k_m, k_v,
                                      v_g, v_b, v_m, v_v,
                                      qs, ks2, vs2, fcnt, flist);

    k_vout<<<(TBCN / 4) / 256, 256, 0, stream>>>(vs2, vout);
    k_kvsum<<<TT * BB, 256, 0, stream>>>(ks2, vs2, kvsum);
    k_thlif<<<BB, CC, 0, stream>>>(kvsum, th_w, kvm);

    k_proj_i8<<<gg, 256, 0, stream>>>(qs, kvm, wq + 3ull * 3 * CCC, pr_b,
                                      p_g, p_b, p_m, p_v, x, out);
}

// Round 9
// 212.348 us; speedup vs baseline: 3.3654x; 1.0612x over previous
//
#include <hip/hip_runtime.h>
#include <math.h>

typedef int i32x4 __attribute__((ext_vector_type(4)));
typedef unsigned long long u64;

constexpr int TT = 4;
constexpr int BB = 32;
constexpr int CC = 384;
constexpr int NN = 256;
constexpr int HEADS = 8;
constexpr int HD = 48;
constexpr int BCN = BB * CC * NN;
constexpr int TBCN = TT * BCN;          // 12,582,912
constexpr int CCC = CC * CC;            // 147,456
constexpr float MARGIN = 1e-4f;         // LIF margin triggering np-exact recompute
constexpr unsigned FCAP = 262144;       // flag list capacity

// ---------------------------------------------------------------------------
// LDS: double-buffered staging (+ repack region for branch kernel)
// ---------------------------------------------------------------------------
struct LdsB {
    unsigned char W[2][3][64][32];   // [buf][plane][o][k]  12 KB
    unsigned char S[2][4][32][32];   // [buf][t][n][k]       8 KB
    unsigned char R[4][32][64];      // spike repack         8 KB
};
struct LdsP {
    unsigned char W[2][3][64][32];
    unsigned char S[2][4][32][32];
};

// ---------------------------------------------------------------------------
// Kernel 0: quantize fp32 weights -> 3 signed-i8 digit planes of round(w*2^23)
// ---------------------------------------------------------------------------
__global__ __launch_bounds__(256) void k_wsplit(
    const float* __restrict__ qw, const float* __restrict__ kw,
    const float* __restrict__ vw, const float* __restrict__ pw,
    signed char* __restrict__ wq, unsigned* __restrict__ cnt) {
    if (blockIdx.x == 0 && threadIdx.x == 0) *cnt = 0u;
    int idx = blockIdx.x * 256 + threadIdx.x;     // 4*CCC total
    int mat = idx / CCC, r = idx % CCC;
    const float* src = (mat == 0) ? qw : (mat == 1) ? kw : (mat == 2) ? vw : pw;
    double w = (double)src[r];
    long long W = llround(w * 8388608.0);         // w * 2^23
    signed char d0 = (signed char)(W & 0xff); W = (W - d0) >> 8;
    signed char d1 = (signed char)(W & 0xff); W = (W - d1) >> 8;
    signed char d2 = (signed char)W;
    size_t base = (size_t)mat * 3 * CCC;
    wq[base + 0 * CCC + r] = d0;
    wq[base + 1 * CCC + r] = d1;
    wq[base + 2 * CCC + r] = d2;
}

// ---------------------------------------------------------------------------
// Kernel 1: shortcut LIF on x [t,b,c,n] -> u8 spikes xs in [t,b,n,c]
// ---------------------------------------------------------------------------
__global__ __launch_bounds__(256) void k_lif_x(const float* __restrict__ x,
                                               unsigned char* __restrict__ xs) {
    __shared__ unsigned char sL[4][64][64];
    const int b_ = blockIdx.x, c0 = blockIdx.y * 64, n0 = blockIdx.z * 64;
    const int tid = threadIdx.x;

    float vm[4][4];
#pragma unroll
    for (int a = 0; a < 4; ++a)
#pragma unroll
        for (int j = 0; j < 4; ++j) vm[a][j] = 0.f;

#pragma unroll
    for (int t = 0; t < TT; ++t) {
#pragma unroll
        for (int a = 0; a < 4; ++a) {
            int idx = tid + 256 * a;
            int ci = idx >> 4, nj4 = idx & 15;
            float4 xv = *(const float4*)&x[((size_t)((t * BB + b_) * CC) + c0 + ci) * NN + n0 + nj4 * 4];
            float xa[4] = {xv.x, xv.y, xv.z, xv.w};
#pragma unroll
            for (int j = 0; j < 4; ++j) {
                vm[a][j] = __fadd_rn(vm[a][j], __fmul_rn(__fsub_rn(xa[j], vm[a][j]), 0.5f));
                int s = (vm[a][j] >= 0.5f);
                sL[t][nj4 * 4 + j][ci] = (unsigned char)s;
                if (s) vm[a][j] = 0.f;
            }
        }
    }
    __syncthreads();
#pragma unroll
    for (int i = 0; i < 16; ++i) {
        int s = tid + 256 * i;
        int c4 = s & 15, n = (s >> 4) & 63, t = s >> 10;
        *(uchar4*)&xs[((size_t)((t * BB + b_) * NN) + n0 + n) * CC + c0 + c4 * 4] =
            *(const uchar4*)&sL[t][n][c4 * 4];
    }
}

// ---------------------------------------------------------------------------
// Kernel 2: FUSED q/k/v branch GEMM. 3-plane i8 MFMA, LDS double-buffered,
// ONE barrier per K-step, prefetch next step's global loads under compute.
// Grid (B, 3*6, 8): mat = by/6, ob = (by%6)*64, nb = bz*32.
// ---------------------------------------------------------------------------
__global__ __launch_bounds__(256, 2) void k_branch_i8(
    const unsigned char* __restrict__ xs, const signed char* __restrict__ wq0,
    const float* __restrict__ qg, const float* __restrict__ qb,
    const float* __restrict__ qm, const float* __restrict__ qv,
    const float* __restrict__ kg_, const float* __restrict__ kb_,
    const float* __restrict__ km_, const float* __restrict__ kv_,
    const float* __restrict__ vg, const float* __restrict__ vb,
    const float* __restrict__ vm_, const float* __restrict__ vv_,
    unsigned char* __restrict__ qs, unsigned char* __restrict__ ks,
    unsigned char* __restrict__ vs,
    unsigned* __restrict__ cnt, unsigned* __restrict__ list) {
    __shared__ LdsB L;
    const int b_ = blockIdx.x;
    const int mat = blockIdx.y / 6, ob = (blockIdx.y % 6) * 64, nb = blockIdx.z * 32;
    const int tid = threadIdx.x, lane = tid & 63, w = tid >> 6;
    const int lo16 = lane & 15, hi4 = lane >> 4;

    const signed char* wq = wq0 + (size_t)mat * 3 * CCC;
    const float* gg  = (mat == 0) ? qg : (mat == 1) ? kg_ : vg;
    const float* bbp = (mat == 0) ? qb : (mat == 1) ? kb_ : vb;
    const float* mmp = (mat == 0) ? qm : (mat == 1) ? km_ : vm_;
    const float* vvp = (mat == 0) ? qv : (mat == 1) ? kv_ : vv_;
    unsigned char* spk = (mat == 0) ? qs : (mat == 1) ? ks : vs;

    // per-thread staging slots
    const int wo = tid >> 2, wkg = tid & 3;                       // weights
    const size_t wroff = (size_t)(ob + wo) * CC + wkg * 8;
    const int e0 = tid, e1 = tid + 256;                           // spikes
    const int t0 = e0 >> 7, n0_ = (e0 & 127) >> 2, kg0 = e0 & 3;
    const int t1 = e1 >> 7, n1_ = (e1 & 127) >> 2, kg1 = e1 & 3;
    const size_t sr0 = ((size_t)((t0 * BB + b_) * NN) + nb + n0_) * CC + kg0 * 8;
    const size_t sr1 = ((size_t)((t1 * BB + b_) * NN) + nb + n1_) * CC + kg1 * 8;

    i32x4 acc[3][4][2];
#pragma unroll
    for (int p = 0; p < 3; ++p)
#pragma unroll
        for (int t = 0; t < 4; ++t)
#pragma unroll
            for (int nf = 0; nf < 2; ++nf) acc[p][t][nf] = (i32x4){0, 0, 0, 0};

    u64 rw0, rw1, rw2, rs0, rs1;
    auto LOAD = [&](int k0) {
        rw0 = *(const u64*)&wq[0 * CCC + wroff + k0];
        rw1 = *(const u64*)&wq[1 * CCC + wroff + k0];
        rw2 = *(const u64*)&wq[2 * CCC + wroff + k0];
        rs0 = *(const u64*)&xs[sr0 + k0];
        rs1 = *(const u64*)&xs[sr1 + k0];
    };
    auto STORE = [&](int buf) {
        *(u64*)&L.W[buf][0][wo][wkg * 8] = rw0;
        *(u64*)&L.W[buf][1][wo][wkg * 8] = rw1;
        *(u64*)&L.W[buf][2][wo][wkg * 8] = rw2;
        *(u64*)&L.S[buf][t0][n0_][kg0 * 8] = rs0;
        *(u64*)&L.S[buf][t1][n1_][kg1 * 8] = rs1;
    };

    LOAD(0);
    STORE(0);
    int cur = 0;
    for (int s = 0; s < 12; ++s) {
        __syncthreads();                       // buf[cur] ready; prev readers of buf[cur^1] done
        if (s < 11) LOAD((s + 1) * 32);        // prefetch next step under compute
        u64 af0 = *(const u64*)&L.W[cur][0][w * 16 + lo16][hi4 * 8];
        u64 af1 = *(const u64*)&L.W[cur][1][w * 16 + lo16][hi4 * 8];
        u64 af2 = *(const u64*)&L.W[cur][2][w * 16 + lo16][hi4 * 8];
#pragma unroll
        for (int t = 0; t < 4; ++t)
#pragma unroll
            for (int nf = 0; nf < 2; ++nf) {
                u64 bfr = *(const u64*)&L.S[cur][t][nf * 16 + lo16][hi4 * 8];
                acc[0][t][nf] = __builtin_amdgcn_mfma_i32_16x16x32_i8((long)af0, (long)bfr, acc[0][t][nf], 0, 0, 0);
                acc[1][t][nf] = __builtin_amdgcn_mfma_i32_16x16x32_i8((long)af1, (long)bfr, acc[1][t][nf], 0, 0, 0);
                acc[2][t][nf] = __builtin_amdgcn_mfma_i32_16x16x32_i8((long)af2, (long)bfr, acc[2][t][nf], 0, 0, 0);
            }
        if (s < 11) STORE(cur ^ 1);            // safe: cur^1's readers passed this step's barrier
        cur ^= 1;
    }

    // epilogue: fp32 np-order BN + LIF, margin flagging, spikes into LDS repack
#pragma unroll
    for (int r = 0; r < 4; ++r) {
        const int o = ob + w * 16 + hi4 * 4 + r;
        const float inv = __fdiv_rn(gg[o], __fsqrt_rn(__fadd_rn(vvp[o], 1e-5f)));
        const float mu = mmp[o], be = bbp[o];
#pragma unroll
        for (int nf = 0; nf < 2; ++nf) {
            float vmem = 0.f, mg = 1e9f;
#pragma unroll
            for (int t = 0; t < 4; ++t) {
                long long N = (long long)acc[0][t][nf][r] + 256LL * acc[1][t][nf][r]
                            + 65536LL * acc[2][t][nf][r];
                float dotf = (float)((double)N * 0x1p-23);
                float y = __fadd_rn(__fmul_rn(__fsub_rn(dotf, mu), inv), be);
                vmem = __fadd_rn(vmem, __fmul_rn(__fsub_rn(y, vmem), 0.5f));
                mg = fminf(mg, fabsf(__fsub_rn(vmem, 0.5f)));
                int s = (vmem >= 0.5f);
                L.R[t][nf * 16 + lo16][w * 16 + hi4 * 4 + r] = (unsigned char)s;
                if (s) vmem = 0.f;
            }
            if (mg < MARGIN) {
                unsigned idx = atomicAdd(cnt, 1u);
                int n = nb + nf * 16 + lo16;
                if (idx < FCAP) list[idx] = ((unsigned)mat << 22) | ((unsigned)b_ << 17) |
                                            ((unsigned)o << 8) | (unsigned)n;
            }
        }
    }
    __syncthreads();
#pragma unroll
    for (int i = 0; i < 8; ++i) {
        int e = tid + 256 * i;
        int c4 = e & 15, n = (e >> 4) & 31, t = e >> 9;
        *(uchar4*)&spk[((size_t)((t * BB + b_) * NN) + nb + n) * CC + ob + c4 * 4] =
            *(const uchar4*)&L.R[t][n][c4 * 4];
    }
}

// ---------------------------------------------------------------------------
// Kernel 2b: np-exact fixup of flagged trajectories (block per item).
// ---------------------------------------------------------------------------
__global__ __launch_bounds__(256) void k_fixup(
    const unsigned char* __restrict__ xs,
    const float* __restrict__ qw, const float* __restrict__ kw, const float* __restrict__ vw,
    const float* __restrict__ qg, const float* __restrict__ qb,
    const float* __restrict__ qm, const float* __restrict__ qv,
    const float* __restrict__ kg_, const float* __restrict__ kb_,
    const float* __restrict__ km_, const float* __restrict__ kv_,
    const float* __restrict__ vg, const float* __restrict__ vb,
    const float* __restrict__ vm_, const float* __restrict__ vv_,
    unsigned char* __restrict__ qs, unsigned char* __restrict__ ks,
    unsigned char* __restrict__ vs,
    const unsigned* __restrict__ cnt, const unsigned* __restrict__ list) {
    __shared__ __align__(16) float sw[CC];
    __shared__ __align__(16) unsigned char sx[TT][CC];
    __shared__ float dots[TT];
    unsigned nfl = *cnt;
    if (nfl > FCAP) nfl = FCAP;
    for (unsigned i = blockIdx.x; i < nfl; i += gridDim.x) {
        unsigned e = list[i];
        int mat = e >> 22, b_ = (e >> 17) & 31, o = (e >> 8) & 511, n = e & 255;
        const float* wbase = (mat == 0) ? qw : (mat == 1) ? kw : vw;
        const float* wrow = wbase + (size_t)o * CC;
        for (int c = threadIdx.x; c < CC; c += 256) sw[c] = wrow[c];
        if (threadIdx.x < TT * (CC / 8)) {
            int t = threadIdx.x / (CC / 8), q = threadIdx.x % (CC / 8);
            *(u64*)&sx[t][q * 8] =
                *(const u64*)&xs[((size_t)((t * BB + b_) * NN) + n) * CC + q * 8];
        }
        __syncthreads();
        if (threadIdx.x < TT) {
            int t = threadIdx.x;
            float acc = 0.f;
            for (int c = 0; c < CC; ++c)
                acc = __fmaf_rn((float)sx[t][c], sw[c], acc);
            dots[t] = acc;
        }
        __syncthreads();
        if (threadIdx.x == 0) {
            const float* G = (mat == 0) ? qg : (mat == 1) ? kg_ : vg;
            const float* Bb = (mat == 0) ? qb : (mat == 1) ? kb_ : vb;
            const float* M = (mat == 0) ? qm : (mat == 1) ? km_ : vm_;
            const float* V = (mat == 0) ? qv : (mat == 1) ? kv_ : vv_;
            unsigned char* S = (mat == 0) ? qs : (mat == 1) ? ks : vs;
            const float inv = __fdiv_rn(G[o], __fsqrt_rn(__fadd_rn(V[o], 1e-5f)));
            const float mu = M[o], be = Bb[o];
            float vmem = 0.f;
            for (int t = 0; t < TT; ++t) {
                float y = __fadd_rn(__fmul_rn(__fsub_rn(dots[t], mu), inv), be);
                vmem = __fadd_rn(vmem, __fmul_rn(__fsub_rn(y, vmem), 0.5f));
                int s = (vmem >= 0.5f);
                S[((size_t)((t * BB + b_) * NN) + n) * CC + o] = (unsigned char)s;
                if (s) vmem = 0.f;
            }
        }
        __syncthreads();
    }
}

// ---------------------------------------------------------------------------
// Kernel 3: v spikes [t,b,n,c] u8 -> f32 out [t,b,h,n,d]
// ---------------------------------------------------------------------------
__global__ __launch_bounds__(256) void k_vout(const unsigned char* __restrict__ vs,
                                              float* __restrict__ vout) {
    int e = blockIdx.x * 256 + threadIdx.x;
    int d4 = e % 12;
    int r = e / 12;
    int n = r & 255;
    r >>= 8;
    int h = r & 7;
    int tb = r >> 3;
    uchar4 u = *(const uchar4*)&vs[((size_t)tb * NN + n) * CC + h * HD + d4 * 4];
    float4 o = {(float)u.x, (float)u.y, (float)u.z, (float)u.w};
    *(float4*)&vout[(((size_t)tb * HEADS + h) * NN + n) * HD + d4 * 4] = o;
}

// ---------------------------------------------------------------------------
// Kernel 4: kvsum[t,b,c] = sum_n k*v  (exact integer)
// ---------------------------------------------------------------------------
__global__ __launch_bounds__(256) void k_kvsum(const unsigned char* __restrict__ ks,
                                               const unsigned char* __restrict__ vs,
                                               int* __restrict__ kvsum) {
    __shared__ int P[5][CC];
    const int tb = blockIdx.x, tid = threadIdx.x;
    if (tid < 240) {
        int c8 = tid % 48, sl = tid / 48;
        int a[8] = {0, 0, 0, 0, 0, 0, 0, 0};
        for (int n = sl; n < NN; n += 5) {
            u64 kk = *(const u64*)&ks[((size_t)tb * NN + n) * CC + c8 * 8];
            u64 vvv = *(const u64*)&vs[((size_t)tb * NN + n) * CC + c8 * 8];
            u64 u = kk & vvv;
#pragma unroll
            for (int j = 0; j < 8; ++j) a[j] += (int)((u >> (8 * j)) & 1);
        }
#pragma unroll
        for (int j = 0; j < 8; ++j) P[sl][c8 * 8 + j] = a[j];
    }
    __syncthreads();
    for (int c = tid; c < CC; c += 256) {
        kvsum[(size_t)tb * CC + c] = P[0][c] + P[1][c] + P[2][c] + P[3][c] + P[4][c];
    }
}

// ---------------------------------------------------------------------------
// Kernel 5: talking heads + LIF, fp32 np-order
// ---------------------------------------------------------------------------
__global__ __launch_bounds__(384) void k_thlif(const int* __restrict__ kvsum,
                                               const float* __restrict__ th,
                                               unsigned char* __restrict__ kvm) {
    __shared__ int kv0[TT][CC];
    const int b_ = blockIdx.x, c = threadIdx.x;
#pragma unroll
    for (int t = 0; t < TT; ++t) kv0[t][c] = kvsum[(size_t)(t * BB + b_) * CC + c];
    __syncthreads();
    const int ho = c / HD, d = c % HD;
    float vmem = 0.f;
#pragma unroll
    for (int t = 0; t < TT; ++t) {
        float s = 0.f;
#pragma unroll
        for (int h = 0; h < HEADS; ++h)
            s = __fadd_rn(s, __fmul_rn(th[ho * HEADS + h], (float)kv0[t][h * HD + d]));
        vmem = __fadd_rn(vmem, __fmul_rn(__fsub_rn(s, vmem), 0.5f));
        int sp = (vmem >= 0.5f);
        kvm[(size_t)(t * BB + b_) * CC + c] = (unsigned char)sp;
        if (sp) vmem = 0.f;
    }
}

// ---------------------------------------------------------------------------
// Kernel 6: proj GEMM (3-plane i8 on q & kvmask), double-buffered like branch;
// fp64 epilogue: +bias, BN, +identity -> f32 out [t,b,c,n]
// ---------------------------------------------------------------------------
__global__ __launch_bounds__(256, 2) void k_proj_i8(
    const unsigned char* __restrict__ qs, const unsigned char* __restrict__ kvm,
    const signed char* __restrict__ wq, const float* __restrict__ pbias,
    const float* __restrict__ gg, const float* __restrict__ bbp,
    const float* __restrict__ mmp, const float* __restrict__ vvp,
    const float* __restrict__ xin, float* __restrict__ out) {
    __shared__ LdsP L;
    const int b_ = blockIdx.x, ob = blockIdx.y * 64, nb = blockIdx.z * 32;
    const int tid = threadIdx.x, lane = tid & 63, w = tid >> 6;
    const int lo16 = lane & 15, hi4 = lane >> 4;

    const int wo = tid >> 2, wkg = tid & 3;
    const size_t wroff = (size_t)(ob + wo) * CC + wkg * 8;
    const int e0 = tid, e1 = tid + 256;
    const int t0 = e0 >> 7, n0_ = (e0 & 127) >> 2, kg0 = e0 & 3;
    const int t1 = e1 >> 7, n1_ = (e1 & 127) >> 2, kg1 = e1 & 3;
    const size_t sr0 = ((size_t)((t0 * BB + b_) * NN) + nb + n0_) * CC + kg0 * 8;
    const size_t sr1 = ((size_t)((t1 * BB + b_) * NN) + nb + n1_) * CC + kg1 * 8;
    const size_t mr0 = (size_t)((t0 * BB + b_) * CC) + kg0 * 8;
    const size_t mr1 = (size_t)((t1 * BB + b_) * CC) + kg1 * 8;

    i32x4 acc[3][4][2];
#pragma unroll
    for (int p = 0; p < 3; ++p)
#pragma unroll
        for (int t = 0; t < 4; ++t)
#pragma unroll
            for (int nf = 0; nf < 2; ++nf) acc[p][t][nf] = (i32x4){0, 0, 0, 0};

    u64 rw0, rw1, rw2, rs0, rs1;
    auto LOAD = [&](int k0) {
        rw0 = *(const u64*)&wq[0 * CCC + wroff + k0];
        rw1 = *(const u64*)&wq[1 * CCC + wroff + k0];
        rw2 = *(const u64*)&wq[2 * CCC + wroff + k0];
        rs0 = *(const u64*)&qs[sr0 + k0] & *(const u64*)&kvm[mr0 + k0];
        rs1 = *(const u64*)&qs[sr1 + k0] & *(const u64*)&kvm[mr1 + k0];
    };
    auto STORE = [&](int buf) {
        *(u64*)&L.W[buf][0][wo][wkg * 8] = rw0;
        *(u64*)&L.W[buf][1][wo][wkg * 8] = rw1;
        *(u64*)&L.W[buf][2][wo][wkg * 8] = rw2;
        *(u64*)&L.S[buf][t0][n0_][kg0 * 8] = rs0;
        *(u64*)&L.S[buf][t1][n1_][kg1 * 8] = rs1;
    };

    LOAD(0);
    STORE(0);
    int cur = 0;
    for (int s = 0; s < 12; ++s) {
        __syncthreads();
        if (s < 11) LOAD((s + 1) * 32);
        u64 af0 = *(const u64*)&L.W[cur][0][w * 16 + lo16][hi4 * 8];
        u64 af1 = *(const u64*)&L.W[cur][1][w * 16 + lo16][hi4 * 8];
        u64 af2 = *(const u64*)&L.W[cur][2][w * 16 + lo16][hi4 * 8];
#pragma unroll
        for (int t = 0; t < 4; ++t)
#pragma unroll
            for (int nf = 0; nf < 2; ++nf) {
                u64 bfr = *(const u64*)&L.S[cur][t][nf * 16 + lo16][hi4 * 8];
                acc[0][t][nf] = __builtin_amdgcn_mfma_i32_16x16x32_i8((long)af0, (long)bfr, acc[0][t][nf], 0, 0, 0);
                acc[1][t][nf] = __builtin_amdgcn_mfma_i32_16x16x32_i8((long)af1, (long)bfr, acc[1][t][nf], 0, 0, 0);
                acc[2][t][nf] = __builtin_amdgcn_mfma_i32_16x16x32_i8((long)af2, (long)bfr, acc[2][t][nf], 0, 0, 0);
            }
        if (s < 11) STORE(cur ^ 1);
        cur ^= 1;
    }

#pragma unroll
    for (int r = 0; r < 4; ++r) {
        const int o = ob + w * 16 + hi4 * 4 + r;
        const double inv = (double)gg[o] / sqrt((double)vvp[o] + 1e-5);
        const double mu = (double)mmp[o], be = (double)bbp[o], pb = (double)pbias[o];
#pragma unroll
        for (int nf = 0; nf < 2; ++nf) {
#pragma unroll
            for (int t = 0; t < 4; ++t) {
                long long N = (long long)acc[0][t][nf][r] + 256LL * acc[1][t][nf][r]
                            + 65536LL * acc[2][t][nf][r];
                double tot = (double)N * 0x1p-23;
                size_t idx = ((size_t)((t * BB + b_) * CC) + o) * NN + nb + nf * 16 + lo16;
                double y = (tot + pb - mu) * inv + be;
                out[idx] = (float)(y + (double)xin[idx]);
            }
        }
    }
}

// ---------------------------------------------------------------------------
extern "C" void kernel_launch(void* const* d_in, const int* in_sizes, int n_in,
                              void* d_out, int out_size, void* d_ws, size_t ws_size,
                              hipStream_t stream) {
    const float* x    = (const float*)d_in[0];
    const float* q_w  = (const float*)d_in[1];
    const float* k_w  = (const float*)d_in[2];
    const float* v_w  = (const float*)d_in[3];
    const float* q_g  = (const float*)d_in[4];
    const float* q_b  = (const float*)d_in[5];
    const float* q_m  = (const float*)d_in[6];
    const float* q_v  = (const float*)d_in[7];
    const float* k_g  = (const float*)d_in[8];
    const float* k_b  = (const float*)d_in[9];
    const float* k_m  = (const float*)d_in[10];
    const float* k_v  = (const float*)d_in[11];
    const float* v_g  = (const float*)d_in[12];
    const float* v_b  = (const float*)d_in[13];
    const float* v_m  = (const float*)d_in[14];
    const float* v_v  = (const float*)d_in[15];
    const float* p_g  = (const float*)d_in[16];
    const float* p_b  = (const float*)d_in[17];
    const float* p_m  = (const float*)d_in[18];
    const float* p_v  = (const float*)d_in[19];
    const float* th_w = (const float*)d_in[20];
    const float* pr_w = (const float*)d_in[21];
    const float* pr_b = (const float*)d_in[22];

    float* out  = (float*)d_out;
    float* vout = out + (size_t)TBCN;

    unsigned char* ws  = (unsigned char*)d_ws;
    unsigned char* xs  = ws;
    unsigned char* qs  = ws + (size_t)TBCN;
    unsigned char* ks2 = ws + (size_t)2 * TBCN;
    unsigned char* vs2 = ws + (size_t)3 * TBCN;
    signed char* wq    = (signed char*)(ws + (size_t)4 * TBCN);          // 4 mats * 3*CCC
    int* kvsum         = (int*)(ws + (size_t)4 * TBCN + 12ull * CCC);
    unsigned char* kvm = (unsigned char*)(kvsum + TT * BB * CC);
    unsigned* fcnt     = (unsigned*)(kvm + (size_t)TT * BB * CC + 64);
    unsigned* flist    = fcnt + 16;

    k_wsplit<<<(4 * CCC) / 256, 256, 0, stream>>>(q_w, k_w, v_w, pr_w, wq, fcnt);
    k_lif_x<<<dim3(BB, CC / 64, NN / 64), 256, 0, stream>>>(x, xs);

    // fused q/k/v branches: grid.y = mat*6 + ob_tile
    k_branch_i8<<<dim3(BB, 18, NN / 32), 256, 0, stream>>>(
        xs, wq,
        q_g, q_b, q_m, q_v,
        k_g, k_b, k_m, k_v,
        v_g, v_b, v_m, v_v,
        qs, ks2, vs2, fcnt, flist);

    k_fixup<<<2048, 256, 0, stream>>>(xs, q_w, k_w, v_w,
                                      q_g, q_b, q_m, q_v,
                                      k_g, k_b, k_m, k_v,
                                      v_g, v_b, v_m, v_v,
                                      qs, ks2, vs2, fcnt, flist);

    k_vout<<<(TBCN / 4) / 256, 256, 0, stream>>>(vs2, vout);
    k_kvsum<<<TT * BB, 256, 0, stream>>>(ks2, vs2, kvsum);
    k_thlif<<<BB, CC, 0, stream>>>(kvsum, th_w, kvm);

    k_proj_i8<<<dim3(BB, CC / 64, NN / 32), 256, 0, stream>>>(
        qs, kvm, wq + 3ull * 3 * CCC, pr_b,
        p_g, p_b, p_m, p_v, x, out);
}

// Round 10
// 167.299 us; speedup vs baseline: 4.2716x; 1.2693x over previous
//
#include <hip/hip_runtime.h>
#include <math.h>

typedef int i32x4 __attribute__((ext_vector_type(4)));
typedef unsigned long long u64;

constexpr int TT = 4;
constexpr int BB = 32;
constexpr int CC = 384;
constexpr int NN = 256;
constexpr int HEADS = 8;
constexpr int HD = 48;
constexpr int BCN = BB * CC * NN;
constexpr int TBCN = TT * BCN;          // 12,582,912
constexpr int CCC = CC * CC;            // 147,456
constexpr float MARGIN = 1e-4f;         // LIF margin triggering np-exact recompute
constexpr unsigned FCAP = 262144;       // flag list capacity

// ---------------------------------------------------------------------------
// LDS: double-buffered staging, 64B rows (K-step = 64)
// ---------------------------------------------------------------------------
struct __align__(16) LdsB {
    unsigned char W[2][3][64][64];   // [buf][plane][o][k]  24 KB
    unsigned char S[2][4][32][64];   // [buf][t][n][k]      16 KB
    unsigned char R[4][32][64];      // spike repack         8 KB
};
struct __align__(16) LdsP {
    unsigned char W[2][3][64][64];
    unsigned char S[2][4][32][64];
};

// ---------------------------------------------------------------------------
// Kernel 0: quantize fp32 weights -> 3 signed-i8 digit planes of round(w*2^23)
// ---------------------------------------------------------------------------
__global__ __launch_bounds__(256) void k_wsplit(
    const float* __restrict__ qw, const float* __restrict__ kw,
    const float* __restrict__ vw, const float* __restrict__ pw,
    signed char* __restrict__ wq, unsigned* __restrict__ cnt) {
    if (blockIdx.x == 0 && threadIdx.x == 0) *cnt = 0u;
    int idx = blockIdx.x * 256 + threadIdx.x;     // 4*CCC total
    int mat = idx / CCC, r = idx % CCC;
    const float* src = (mat == 0) ? qw : (mat == 1) ? kw : (mat == 2) ? vw : pw;
    double w = (double)src[r];
    long long W = llround(w * 8388608.0);         // w * 2^23
    signed char d0 = (signed char)(W & 0xff); W = (W - d0) >> 8;
    signed char d1 = (signed char)(W & 0xff); W = (W - d1) >> 8;
    signed char d2 = (signed char)W;
    size_t base = (size_t)mat * 3 * CCC;
    wq[base + 0 * CCC + r] = d0;
    wq[base + 1 * CCC + r] = d1;
    wq[base + 2 * CCC + r] = d2;
}

// ---------------------------------------------------------------------------
// Kernel 1: shortcut LIF on x [t,b,c,n] -> u8 spikes xs in [t,b,n,c]
// ---------------------------------------------------------------------------
__global__ __launch_bounds__(256) void k_lif_x(const float* __restrict__ x,
                                               unsigned char* __restrict__ xs) {
    __shared__ unsigned char sL[4][64][64];
    const int b_ = blockIdx.x, c0 = blockIdx.y * 64, n0 = blockIdx.z * 64;
    const int tid = threadIdx.x;

    float vm[4][4];
#pragma unroll
    for (int a = 0; a < 4; ++a)
#pragma unroll
        for (int j = 0; j < 4; ++j) vm[a][j] = 0.f;

#pragma unroll
    for (int t = 0; t < TT; ++t) {
#pragma unroll
        for (int a = 0; a < 4; ++a) {
            int idx = tid + 256 * a;
            int ci = idx >> 4, nj4 = idx & 15;
            float4 xv = *(const float4*)&x[((size_t)((t * BB + b_) * CC) + c0 + ci) * NN + n0 + nj4 * 4];
            float xa[4] = {xv.x, xv.y, xv.z, xv.w};
#pragma unroll
            for (int j = 0; j < 4; ++j) {
                vm[a][j] = __fadd_rn(vm[a][j], __fmul_rn(__fsub_rn(xa[j], vm[a][j]), 0.5f));
                int s = (vm[a][j] >= 0.5f);
                sL[t][nj4 * 4 + j][ci] = (unsigned char)s;
                if (s) vm[a][j] = 0.f;
            }
        }
    }
    __syncthreads();
#pragma unroll
    for (int i = 0; i < 16; ++i) {
        int s = tid + 256 * i;
        int c4 = s & 15, n = (s >> 4) & 63, t = s >> 10;
        *(uchar4*)&xs[((size_t)((t * BB + b_) * NN) + n0 + n) * CC + c0 + c4 * 4] =
            *(const uchar4*)&sL[t][n][c4 * 4];
    }
}

// ---------------------------------------------------------------------------
// Kernel 2: FUSED q/k/v branch GEMM. 3-plane mfma_i32_16x16x64_i8 (K-step 64),
// LDS double-buffered 64B rows, one barrier per step, reg prefetch.
// Grid (B, 3*6, 8): mat = by/6, ob = (by%6)*64, nb = bz*32.
// ---------------------------------------------------------------------------
__global__ __launch_bounds__(256, 2) void k_branch_i8(
    const unsigned char* __restrict__ xs, const signed char* __restrict__ wq0,
    const float* __restrict__ qg, const float* __restrict__ qb,
    const float* __restrict__ qm, const float* __restrict__ qv,
    const float* __restrict__ kg_, const float* __restrict__ kb_,
    const float* __restrict__ km_, const float* __restrict__ kv_,
    const float* __restrict__ vg, const float* __restrict__ vb,
    const float* __restrict__ vm_, const float* __restrict__ vv_,
    unsigned char* __restrict__ qs, unsigned char* __restrict__ ks,
    unsigned char* __restrict__ vs,
    unsigned* __restrict__ cnt, unsigned* __restrict__ list) {
    __shared__ LdsB L;
    const int b_ = blockIdx.x;
    const int mat = blockIdx.y / 6, ob = (blockIdx.y % 6) * 64, nb = blockIdx.z * 32;
    const int tid = threadIdx.x, lane = tid & 63, w = tid >> 6;
    const int lo16 = lane & 15, hi4 = lane >> 4;

    const signed char* wq = wq0 + (size_t)mat * 3 * CCC;
    const float* gg  = (mat == 0) ? qg : (mat == 1) ? kg_ : vg;
    const float* bbp = (mat == 0) ? qb : (mat == 1) ? kb_ : vb;
    const float* mmp = (mat == 0) ? qm : (mat == 1) ? km_ : vm_;
    const float* vvp = (mat == 0) ? qv : (mat == 1) ? kv_ : vv_;
    unsigned char* spk = (mat == 0) ? qs : (mat == 1) ? ks : vs;

    // staging slots: weights 3x16B/thread, spikes 2x16B/thread
    const int wo = tid >> 2, wc16 = tid & 3;
    const size_t wroff = (size_t)(ob + wo) * CC + wc16 * 16;
    const int e0 = tid, e1 = tid + 256;
    const int t0 = e0 >> 7, n0_ = (e0 >> 2) & 31, c0_ = e0 & 3;
    const int t1 = e1 >> 7, n1_ = (e1 >> 2) & 31, c1_ = e1 & 3;
    const size_t sr0 = ((size_t)((t0 * BB + b_) * NN) + nb + n0_) * CC + c0_ * 16;
    const size_t sr1 = ((size_t)((t1 * BB + b_) * NN) + nb + n1_) * CC + c1_ * 16;

    i32x4 acc[3][4][2];
#pragma unroll
    for (int p = 0; p < 3; ++p)
#pragma unroll
        for (int t = 0; t < 4; ++t)
#pragma unroll
            for (int nf = 0; nf < 2; ++nf) acc[p][t][nf] = (i32x4){0, 0, 0, 0};

    i32x4 rw0, rw1, rw2, rs0, rs1;
    auto LOAD = [&](int k0) {
        rw0 = *(const i32x4*)&wq[0 * CCC + wroff + k0];
        rw1 = *(const i32x4*)&wq[1 * CCC + wroff + k0];
        rw2 = *(const i32x4*)&wq[2 * CCC + wroff + k0];
        rs0 = *(const i32x4*)&xs[sr0 + k0];
        rs1 = *(const i32x4*)&xs[sr1 + k0];
    };
    auto STORE = [&](int buf) {
        *(i32x4*)&L.W[buf][0][wo][wc16 * 16] = rw0;
        *(i32x4*)&L.W[buf][1][wo][wc16 * 16] = rw1;
        *(i32x4*)&L.W[buf][2][wo][wc16 * 16] = rw2;
        *(i32x4*)&L.S[buf][t0][n0_][c0_ * 16] = rs0;
        *(i32x4*)&L.S[buf][t1][n1_][c1_ * 16] = rs1;
    };

    LOAD(0);
    STORE(0);
    int cur = 0;
    for (int s = 0; s < 6; ++s) {
        __syncthreads();                       // buf[cur] ready; buf[cur^1] readers done
        if (s < 5) LOAD((s + 1) * 64);         // prefetch next step under compute
        i32x4 af0 = *(const i32x4*)&L.W[cur][0][w * 16 + lo16][hi4 * 16];
        i32x4 af1 = *(const i32x4*)&L.W[cur][1][w * 16 + lo16][hi4 * 16];
        i32x4 af2 = *(const i32x4*)&L.W[cur][2][w * 16 + lo16][hi4 * 16];
#pragma unroll
        for (int t = 0; t < 4; ++t)
#pragma unroll
            for (int nf = 0; nf < 2; ++nf) {
                i32x4 bfr = *(const i32x4*)&L.S[cur][t][nf * 16 + lo16][hi4 * 16];
                acc[0][t][nf] = __builtin_amdgcn_mfma_i32_16x16x64_i8(af0, bfr, acc[0][t][nf], 0, 0, 0);
                acc[1][t][nf] = __builtin_amdgcn_mfma_i32_16x16x64_i8(af1, bfr, acc[1][t][nf], 0, 0, 0);
                acc[2][t][nf] = __builtin_amdgcn_mfma_i32_16x16x64_i8(af2, bfr, acc[2][t][nf], 0, 0, 0);
            }
        if (s < 5) STORE(cur ^ 1);
        cur ^= 1;
    }

    // epilogue: fp32 np-order BN + LIF, margin flagging, spikes into LDS repack
#pragma unroll
    for (int r = 0; r < 4; ++r) {
        const int o = ob + w * 16 + hi4 * 4 + r;
        const float inv = __fdiv_rn(gg[o], __fsqrt_rn(__fadd_rn(vvp[o], 1e-5f)));
        const float mu = mmp[o], be = bbp[o];
#pragma unroll
        for (int nf = 0; nf < 2; ++nf) {
            float vmem = 0.f, mg = 1e9f;
#pragma unroll
            for (int t = 0; t < 4; ++t) {
                long long N = (long long)acc[0][t][nf][r] + 256LL * acc[1][t][nf][r]
                            + 65536LL * acc[2][t][nf][r];
                float dotf = (float)((double)N * 0x1p-23);
                float y = __fadd_rn(__fmul_rn(__fsub_rn(dotf, mu), inv), be);
                vmem = __fadd_rn(vmem, __fmul_rn(__fsub_rn(y, vmem), 0.5f));
                mg = fminf(mg, fabsf(__fsub_rn(vmem, 0.5f)));
                int s = (vmem >= 0.5f);
                L.R[t][nf * 16 + lo16][w * 16 + hi4 * 4 + r] = (unsigned char)s;
                if (s) vmem = 0.f;
            }
            if (mg < MARGIN) {
                unsigned idx = atomicAdd(cnt, 1u);
                int n = nb + nf * 16 + lo16;
                if (idx < FCAP) list[idx] = ((unsigned)mat << 22) | ((unsigned)b_ << 17) |
                                            ((unsigned)o << 8) | (unsigned)n;
            }
        }
    }
    __syncthreads();
#pragma unroll
    for (int i = 0; i < 8; ++i) {
        int e = tid + 256 * i;
        int c4 = e & 15, n = (e >> 4) & 31, t = e >> 9;
        *(uchar4*)&spk[((size_t)((t * BB + b_) * NN) + nb + n) * CC + ob + c4 * 4] =
            *(const uchar4*)&L.R[t][n][c4 * 4];
    }
}

// ---------------------------------------------------------------------------
// Kernel 2b: np-exact fixup of flagged trajectories (block per item).
// ---------------------------------------------------------------------------
__global__ __launch_bounds__(256) void k_fixup(
    const unsigned char* __restrict__ xs,
    const float* __restrict__ qw, const float* __restrict__ kw, const float* __restrict__ vw,
    const float* __restrict__ qg, const float* __restrict__ qb,
    const float* __restrict__ qm, const float* __restrict__ qv,
    const float* __restrict__ kg_, const float* __restrict__ kb_,
    const float* __restrict__ km_, const float* __restrict__ kv_,
    const float* __restrict__ vg, const float* __restrict__ vb,
    const float* __restrict__ vm_, const float* __restrict__ vv_,
    unsigned char* __restrict__ qs, unsigned char* __restrict__ ks,
    unsigned char* __restrict__ vs,
    const unsigned* __restrict__ cnt, const unsigned* __restrict__ list) {
    __shared__ __align__(16) float sw[CC];
    __shared__ __align__(16) unsigned char sx[TT][CC];
    __shared__ float dots[TT];
    unsigned nfl = *cnt;
    if (nfl > FCAP) nfl = FCAP;
    for (unsigned i = blockIdx.x; i < nfl; i += gridDim.x) {
        unsigned e = list[i];
        int mat = e >> 22, b_ = (e >> 17) & 31, o = (e >> 8) & 511, n = e & 255;
        const float* wbase = (mat == 0) ? qw : (mat == 1) ? kw : vw;
        const float* wrow = wbase + (size_t)o * CC;
        for (int c = threadIdx.x; c < CC; c += 256) sw[c] = wrow[c];
        if (threadIdx.x < TT * (CC / 8)) {
            int t = threadIdx.x / (CC / 8), q = threadIdx.x % (CC / 8);
            *(u64*)&sx[t][q * 8] =
                *(const u64*)&xs[((size_t)((t * BB + b_) * NN) + n) * CC + q * 8];
        }
        __syncthreads();
        if (threadIdx.x < TT) {
            int t = threadIdx.x;
            float acc = 0.f;
            for (int c = 0; c < CC; ++c)
                acc = __fmaf_rn((float)sx[t][c], sw[c], acc);
            dots[t] = acc;
        }
        __syncthreads();
        if (threadIdx.x == 0) {
            const float* G = (mat == 0) ? qg : (mat == 1) ? kg_ : vg;
            const float* Bb = (mat == 0) ? qb : (mat == 1) ? kb_ : vb;
            const float* M = (mat == 0) ? qm : (mat == 1) ? km_ : vm_;
            const float* V = (mat == 0) ? qv : (mat == 1) ? kv_ : vv_;
            unsigned char* S = (mat == 0) ? qs : (mat == 1) ? ks : vs;
            const float inv = __fdiv_rn(G[o], __fsqrt_rn(__fadd_rn(V[o], 1e-5f)));
            const float mu = M[o], be = Bb[o];
            float vmem = 0.f;
            for (int t = 0; t < TT; ++t) {
                float y = __fadd_rn(__fmul_rn(__fsub_rn(dots[t], mu), inv), be);
                vmem = __fadd_rn(vmem, __fmul_rn(__fsub_rn(y, vmem), 0.5f));
                int s = (vmem >= 0.5f);
                S[((size_t)((t * BB + b_) * NN) + n) * CC + o] = (unsigned char)s;
                if (s) vmem = 0.f;
            }
        }
        __syncthreads();
    }
}

// ---------------------------------------------------------------------------
// Kernel 3: v spikes [t,b,n,c] u8 -> f32 out [t,b,h,n,d]
// ---------------------------------------------------------------------------
__global__ __launch_bounds__(256) void k_vout(const unsigned char* __restrict__ vs,
                                              float* __restrict__ vout) {
    int e = blockIdx.x * 256 + threadIdx.x;
    int d4 = e % 12;
    int r = e / 12;
    int n = r & 255;
    r >>= 8;
    int h = r & 7;
    int tb = r >> 3;
    uchar4 u = *(const uchar4*)&vs[((size_t)tb * NN + n) * CC + h * HD + d4 * 4];
    float4 o = {(float)u.x, (float)u.y, (float)u.z, (float)u.w};
    *(float4*)&vout[(((size_t)tb * HEADS + h) * NN + n) * HD + d4 * 4] = o;
}

// ---------------------------------------------------------------------------
// Kernel 4: kvsum[t,b,c] = sum_n k*v  (exact integer)
// ---------------------------------------------------------------------------
__global__ __launch_bounds__(256) void k_kvsum(const unsigned char* __restrict__ ks,
                                               const unsigned char* __restrict__ vs,
                                               int* __restrict__ kvsum) {
    __shared__ int P[5][CC];
    const int tb = blockIdx.x, tid = threadIdx.x;
    if (tid < 240) {
        int c8 = tid % 48, sl = tid / 48;
        int a[8] = {0, 0, 0, 0, 0, 0, 0, 0};
        for (int n = sl; n < NN; n += 5) {
            u64 kk = *(const u64*)&ks[((size_t)tb * NN + n) * CC + c8 * 8];
            u64 vvv = *(const u64*)&vs[((size_t)tb * NN + n) * CC + c8 * 8];
            u64 u = kk & vvv;
#pragma unroll
            for (int j = 0; j < 8; ++j) a[j] += (int)((u >> (8 * j)) & 1);
        }
#pragma unroll
        for (int j = 0; j < 8; ++j) P[sl][c8 * 8 + j] = a[j];
    }
    __syncthreads();
    for (int c = tid; c < CC; c += 256) {
        kvsum[(size_t)tb * CC + c] = P[0][c] + P[1][c] + P[2][c] + P[3][c] + P[4][c];
    }
}

// ---------------------------------------------------------------------------
// Kernel 5: talking heads + LIF, fp32 np-order
// ---------------------------------------------------------------------------
__global__ __launch_bounds__(384) void k_thlif(const int* __restrict__ kvsum,
                                               const float* __restrict__ th,
                                               unsigned char* __restrict__ kvm) {
    __shared__ int kv0[TT][CC];
    const int b_ = blockIdx.x, c = threadIdx.x;
#pragma unroll
    for (int t = 0; t < TT; ++t) kv0[t][c] = kvsum[(size_t)(t * BB + b_) * CC + c];
    __syncthreads();
    const int ho = c / HD, d = c % HD;
    float vmem = 0.f;
#pragma unroll
    for (int t = 0; t < TT; ++t) {
        float s = 0.f;
#pragma unroll
        for (int h = 0; h < HEADS; ++h)
            s = __fadd_rn(s, __fmul_rn(th[ho * HEADS + h], (float)kv0[t][h * HD + d]));
        vmem = __fadd_rn(vmem, __fmul_rn(__fsub_rn(s, vmem), 0.5f));
        int sp = (vmem >= 0.5f);
        kvm[(size_t)(t * BB + b_) * CC + c] = (unsigned char)sp;
        if (sp) vmem = 0.f;
    }
}

// ---------------------------------------------------------------------------
// Kernel 6: proj GEMM (3-plane K=64 i8 on q & kvmask), double-buffered;
// fp64 epilogue: +bias, BN, +identity -> f32 out [t,b,c,n]
// ---------------------------------------------------------------------------
__global__ __launch_bounds__(256, 2) void k_proj_i8(
    const unsigned char* __restrict__ qs, const unsigned char* __restrict__ kvm,
    const signed char* __restrict__ wq, const float* __restrict__ pbias,
    const float* __restrict__ gg, const float* __restrict__ bbp,
    const float* __restrict__ mmp, const float* __restrict__ vvp,
    const float* __restrict__ xin, float* __restrict__ out) {
    __shared__ LdsP L;
    const int b_ = blockIdx.x, ob = blockIdx.y * 64, nb = blockIdx.z * 32;
    const int tid = threadIdx.x, lane = tid & 63, w = tid >> 6;
    const int lo16 = lane & 15, hi4 = lane >> 4;

    const int wo = tid >> 2, wc16 = tid & 3;
    const size_t wroff = (size_t)(ob + wo) * CC + wc16 * 16;
    const int e0 = tid, e1 = tid + 256;
    const int t0 = e0 >> 7, n0_ = (e0 >> 2) & 31, c0_ = e0 & 3;
    const int t1 = e1 >> 7, n1_ = (e1 >> 2) & 31, c1_ = e1 & 3;
    const size_t sr0 = ((size_t)((t0 * BB + b_) * NN) + nb + n0_) * CC + c0_ * 16;
    const size_t sr1 = ((size_t)((t1 * BB + b_) * NN) + nb + n1_) * CC + c1_ * 16;
    const size_t mr0 = (size_t)((t0 * BB + b_) * CC) + c0_ * 16;
    const size_t mr1 = (size_t)((t1 * BB + b_) * CC) + c1_ * 16;

    i32x4 acc[3][4][2];
#pragma unroll
    for (int p = 0; p < 3; ++p)
#pragma unroll
        for (int t = 0; t < 4; ++t)
#pragma unroll
            for (int nf = 0; nf < 2; ++nf) acc[p][t][nf] = (i32x4){0, 0, 0, 0};

    i32x4 rw0, rw1, rw2, rs0, rs1;
    auto LOAD = [&](int k0) {
        rw0 = *(const i32x4*)&wq[0 * CCC + wroff + k0];
        rw1 = *(const i32x4*)&wq[1 * CCC + wroff + k0];
        rw2 = *(const i32x4*)&wq[2 * CCC + wroff + k0];
        i32x4 q0 = *(const i32x4*)&qs[sr0 + k0];
        i32x4 m0 = *(const i32x4*)&kvm[mr0 + k0];
        i32x4 q1 = *(const i32x4*)&qs[sr1 + k0];
        i32x4 m1 = *(const i32x4*)&kvm[mr1 + k0];
        rs0 = q0 & m0;
        rs1 = q1 & m1;
    };
    auto STORE = [&](int buf) {
        *(i32x4*)&L.W[buf][0][wo][wc16 * 16] = rw0;
        *(i32x4*)&L.W[buf][1][wo][wc16 * 16] = rw1;
        *(i32x4*)&L.W[buf][2][wo][wc16 * 16] = rw2;
        *(i32x4*)&L.S[buf][t0][n0_][c0_ * 16] = rs0;
        *(i32x4*)&L.S[buf][t1][n1_][c1_ * 16] = rs1;
    };

    LOAD(0);
    STORE(0);
    int cur = 0;
    for (int s = 0; s < 6; ++s) {
        __syncthreads();
        if (s < 5) LOAD((s + 1) * 64);
        i32x4 af0 = *(const i32x4*)&L.W[cur][0][w * 16 + lo16][hi4 * 16];
        i32x4 af1 = *(const i32x4*)&L.W[cur][1][w * 16 + lo16][hi4 * 16];
        i32x4 af2 = *(const i32x4*)&L.W[cur][2][w * 16 + lo16][hi4 * 16];
#pragma unroll
        for (int t = 0; t < 4; ++t)
#pragma unroll
            for (int nf = 0; nf < 2; ++nf) {
                i32x4 bfr = *(const i32x4*)&L.S[cur][t][nf * 16 + lo16][hi4 * 16];
                acc[0][t][nf] = __builtin_amdgcn_mfma_i32_16x16x64_i8(af0, bfr, acc[0][t][nf], 0, 0, 0);
                acc[1][t][nf] = __builtin_amdgcn_mfma_i32_16x16x64_i8(af1, bfr, acc[1][t][nf], 0, 0, 0);
                acc[2][t][nf] = __builtin_amdgcn_mfma_i32_16x16x64_i8(af2, bfr, acc[2][t][nf], 0, 0, 0);
            }
        if (s < 5) STORE(cur ^ 1);
        cur ^= 1;
    }

#pragma unroll
    for (int r = 0; r < 4; ++r) {
        const int o = ob + w * 16 + hi4 * 4 + r;
        const double inv = (double)gg[o] / sqrt((double)vvp[o] + 1e-5);
        const double mu = (double)mmp[o], be = (double)bbp[o], pb = (double)pbias[o];
#pragma unroll
        for (int nf = 0; nf < 2; ++nf) {
#pragma unroll
            for (int t = 0; t < 4; ++t) {
                long long N = (long long)acc[0][t][nf][r] + 256LL * acc[1][t][nf][r]
                            + 65536LL * acc[2][t][nf][r];
                double tot = (double)N * 0x1p-23;
                size_t idx = ((size_t)((t * BB + b_) * CC) + o) * NN + nb + nf * 16 + lo16;
                double y = (tot + pb - mu) * inv + be;
                out[idx] = (float)(y + (double)xin[idx]);
            }
        }
    }
}

// ---------------------------------------------------------------------------
extern "C" void kernel_launch(void* const* d_in, const int* in_sizes, int n_in,
                              void* d_out, int out_size, void* d_ws, size_t ws_size,
                              hipStream_t stream) {
    const float* x    = (const float*)d_in[0];
    const float* q_w  = (const float*)d_in[1];
    const float* k_w  = (const float*)d_in[2];
    const float* v_w  = (const float*)d_in[3];
    const float* q_g  = (const float*)d_in[4];
    const float* q_b  = (const float*)d_in[5];
    const float* q_m  = (const float*)d_in[6];
    const float* q_v  = (const float*)d_in[7];
    const float* k_g  = (const float*)d_in[8];
    const float* k_b  = (const float*)d_in[9];
    const float* k_m  = (const float*)d_in[10];
    const float* k_v  = (const float*)d_in[11];
    const float* v_g  = (const float*)d_in[12];
    const float* v_b  = (const float*)d_in[13];
    const float* v_m  = (const float*)d_in[14];
    const float* v_v  = (const float*)d_in[15];
    const float* p_g  = (const float*)d_in[16];
    const float* p_b  = (const float*)d_in[17];
    const float* p_m  = (const float*)d_in[18];
    const float* p_v  = (const float*)d_in[19];
    const float* th_w = (const float*)d_in[20];
    const float* pr_w = (const float*)d_in[21];
    const float* pr_b = (const float*)d_in[22];

    float* out  = (float*)d_out;
    float* vout = out + (size_t)TBCN;

    unsigned char* ws  = (unsigned char*)d_ws;
    unsigned char* xs  = ws;
    unsigned char* qs  = ws + (size_t)TBCN;
    unsigned char* ks2 = ws + (size_t)2 * TBCN;
    unsigned char* vs2 = ws + (size_t)3 * TBCN;
    signed char* wq    = (signed char*)(ws + (size_t)4 * TBCN);          // 4 mats * 3*CCC
    int* kvsum         = (int*)(ws + (size_t)4 * TBCN + 12ull * CCC);
    unsigned char* kvm = (unsigned char*)(kvsum + TT * BB * CC);
    unsigned* fcnt     = (unsigned*)(kvm + (size_t)TT * BB * CC + 64);
    unsigned* flist    = fcnt + 16;

    k_wsplit<<<(4 * CCC) / 256, 256, 0, stream>>>(q_w, k_w, v_w, pr_w, wq, fcnt);
    k_lif_x<<<dim3(BB, CC / 64, NN / 64), 256, 0, stream>>>(x, xs);

    // fused q/k/v branches: grid.y = mat*6 + ob_tile
    k_branch_i8<<<dim3(BB, 18, NN / 32), 256, 0, stream>>>(
        xs, wq,
        q_g, q_b, q_m, q_v,
        k_g, k_b, k_m, k_v,
        v_g, v_b, v_m, v_v,
        qs, ks2, vs2, fcnt, flist);

    k_fixup<<<2048, 256, 0, stream>>>(xs, q_w, k_w, v_w,
                                      q_g, q_b, q_m, q_v,
                                      k_g, k_b, k_m, k_v,
                                      v_g, v_b, v_m, v_v,
                                      qs, ks2, vs2, fcnt, flist);

    k_vout<<<(TBCN / 4) / 256, 256, 0, stream>>>(vs2, vout);
    k_kvsum<<<TT * BB, 256, 0, stream>>>(ks2, vs2, kvsum);
    k_thlif<<<BB, CC, 0, stream>>>(kvsum, th_w, kvm);

    k_proj_i8<<<dim3(BB, CC / 64, NN / 32), 256, 0, stream>>>(
        qs, kvm, wq + 3ull * 3 * CCC, pr_b,
        p_g, p_b, p_m, p_v, x, out);
}